// Round 1
// baseline (532.713 us; speedup 1.0000x reference)
//
#include <hip/hip_runtime.h>

typedef unsigned short u16;
typedef __attribute__((ext_vector_type(8))) __bf16 bf16x8;
typedef __attribute__((ext_vector_type(4))) float f32x4;
typedef __attribute__((ext_vector_type(4))) unsigned short u16x4;

#define AS1 __attribute__((address_space(1)))
#define AS3 __attribute__((address_space(3)))

__device__ __forceinline__ void async_load16(const void* g, void* l) {
  __builtin_amdgcn_global_load_lds((const AS1 void*)g, (AS3 void*)l, 16, 0, 0);
}

__device__ __forceinline__ u16 f2bf(float f) {
  union { float f; unsigned u; } a; a.f = f;
  unsigned u = a.u;
  u += 0x7fffu + ((u >> 16) & 1u);   // RNE
  return (u16)(u >> 16);
}

// ---------------- fp32 -> bf16 convert (weights) ----------------
__global__ __launch_bounds__(256)
void f2b_kernel(const float* __restrict__ s, u16* __restrict__ d, int n4) {
  int i = blockIdx.x * 256 + threadIdx.x;
  if (i >= n4) return;
  const float4 v = ((const float4*)s)[i];
  u16x4 o; o[0] = f2bf(v.x); o[1] = f2bf(v.y); o[2] = f2bf(v.z); o[3] = f2bf(v.w);
  ((u16x4*)d)[i] = o;
}

// ---------------- LayerNorm (1024 cols, 1 block/row) ----------------
__global__ __launch_bounds__(256)
void ln_kernel(const float* __restrict__ x, const float* __restrict__ g,
               const float* __restrict__ b, u16* __restrict__ out) {
  const int row = blockIdx.x, tid = threadIdx.x;
  const float4 v = ((const float4*)(x + (size_t)row * 1024))[tid];
  float s = v.x + v.y + v.z + v.w;
  float s2 = v.x * v.x + v.y * v.y + v.z * v.z + v.w * v.w;
#pragma unroll
  for (int o = 1; o < 64; o <<= 1) { s += __shfl_xor(s, o); s2 += __shfl_xor(s2, o); }
  __shared__ float red[8];
  const int wave = tid >> 6, lane = tid & 63;
  if (lane == 0) { red[wave] = s; red[wave + 4] = s2; }
  __syncthreads();
  s = red[0] + red[1] + red[2] + red[3];
  s2 = red[4] + red[5] + red[6] + red[7];
  const float mu = s * (1.f / 1024.f);
  const float rstd = rsqrtf(s2 * (1.f / 1024.f) - mu * mu + 1e-5f);
  const float4 gg = ((const float4*)g)[tid];
  const float4 bb = ((const float4*)b)[tid];
  u16x4 o4;
  o4[0] = f2bf((v.x - mu) * rstd * gg.x + bb.x);
  o4[1] = f2bf((v.y - mu) * rstd * gg.y + bb.y);
  o4[2] = f2bf((v.z - mu) * rstd * gg.z + bb.z);
  o4[3] = f2bf((v.w - mu) * rstd * gg.w + bb.w);
  ((u16x4*)(out + (size_t)row * 1024))[tid] = o4;
}

// ---------------- GEMM C = A * B^T, A[M,K] bf16, B[N,K] bf16 ----------------
// 128x128 tile, BK=32, 4 waves (2x2), each wave 4x4 mfma 16x16x32. m97 structure.
template <class Epi>
__global__ __launch_bounds__(256)
void gemm_bt(const u16* __restrict__ A, const u16* __restrict__ Bw, int K, Epi epi) {
  __shared__ __align__(16) u16 As[128 * 32];
  __shared__ __align__(16) u16 Bs[128 * 32];
  const int tid = threadIdx.x;
  const int wave = tid >> 6, lane = tid & 63;
  const int quad = lane >> 4, l16 = lane & 15;
  const int bm = blockIdx.x * 128, bn = blockIdx.y * 128;
  const int wm = (wave & 1) * 64, wn = (wave >> 1) * 64;

  // staging: wave w issues 2 lds-direct loads per operand; rows w*32+(lane/4) and +16
  const int srow = wave * 32 + (lane >> 2);
  const int scol = (lane & 3) * 8;
  const u16* pa0 = A + (size_t)(bm + srow) * K + scol;
  const u16* pa1 = pa0 + (size_t)16 * K;
  const u16* pb0 = Bw + (size_t)(bn + srow) * K + scol;
  const u16* pb1 = pb0 + (size_t)16 * K;
  u16* la0 = &As[wave * 1024];
  u16* la1 = &As[wave * 1024 + 512];
  u16* lb0 = &Bs[wave * 1024];
  u16* lb1 = &Bs[wave * 1024 + 512];

  const f32x4 fz = {0.f, 0.f, 0.f, 0.f};
  f32x4 acc[4][4];
#pragma unroll
  for (int i = 0; i < 4; i++)
#pragma unroll
    for (int j = 0; j < 4; j++) acc[i][j] = fz;

  for (int k0 = 0; k0 < K; k0 += 32) {
    async_load16(pa0, la0);
    async_load16(pa1, la1);
    async_load16(pb0, lb0);
    async_load16(pb1, lb1);
    pa0 += 32; pa1 += 32; pb0 += 32; pb1 += 32;
    __syncthreads();
    bf16x8 af[4], bf[4];
#pragma unroll
    for (int mi = 0; mi < 4; mi++)
      af[mi] = *(const bf16x8*)&As[(wm + mi * 16 + l16) * 32 + quad * 8];
#pragma unroll
    for (int ni = 0; ni < 4; ni++)
      bf[ni] = *(const bf16x8*)&Bs[(wn + ni * 16 + l16) * 32 + quad * 8];
#pragma unroll
    for (int mi = 0; mi < 4; mi++)
#pragma unroll
      for (int ni = 0; ni < 4; ni++)
        acc[mi][ni] = __builtin_amdgcn_mfma_f32_16x16x32_bf16(af[mi], bf[ni], acc[mi][ni], 0, 0, 0);
    __syncthreads();
  }
#pragma unroll
  for (int mi = 0; mi < 4; mi++)
#pragma unroll
    for (int ni = 0; ni < 4; ni++)
#pragma unroll
      for (int r = 0; r < 4; r++)
        epi(bm + wm + mi * 16 + quad * 4 + r, bn + wn + ni * 16 + l16, acc[mi][ni][r]);
}

// ---------------- epilogues ----------------
struct EpiQKV {   // scatter to q[b,h,s,e] (scaled 0.125), k[b,h,s,e], v^T[b,h,e,s]
  u16 *q, *k, *vt; const float *bq, *bk, *bv;
  __device__ void operator()(int m, int n, float v) const {
    const int which = n >> 10, nn = n & 1023;
    const int hh = nn >> 6, e = nn & 63;
    const int bb = m >> 11, s = m & 2047;
    const size_t bh = (size_t)(bb * 16 + hh);
    if (which == 0)
      q[(bh * 2048 + s) * 64 + e] = f2bf((v + bq[nn]) * 0.125f);
    else if (which == 1)
      k[(bh * 2048 + s) * 64 + e] = f2bf(v + bk[nn]);
    else
      vt[(bh * 64 + e) * 2048 + s] = f2bf(v + bv[nn]);
  }
};
struct EpiO {     // out = x + (attn @ Wo^T + bo)   (fp32)
  const float* x; const float* bo; float* out;
  __device__ void operator()(int m, int n, float v) const {
    const size_t i = (size_t)m * 1024 + n;
    out[i] = x[i] + v + bo[n];
  }
};
struct EpiGelu {  // mlp1 = gelu(h2 @ W1^T + b1)  (bf16)
  const float* b1; u16* o;
  __device__ void operator()(int m, int n, float v) const {
    float u = v + b1[n];
    float z = 0.7978845608f * (u + 0.044715f * u * u * u);
    float t = __expf(2.f * z);          // tanh(z) = 1 - 2/(e^{2z}+1)
    float th = 1.f - 2.f / (t + 1.f);
    o[(size_t)m * 4096 + n] = f2bf(0.5f * u * (1.f + th));
  }
};
struct EpiOut {   // out += mlp1 @ W2^T + b2  (fp32, out already holds x1)
  const float* b2; float* out;
  __device__ void operator()(int m, int n, float v) const {
    const size_t i = (size_t)m * 1024 + n;
    out[i] += v + b2[n];
  }
};

// ---------------- flash attention (no mask), 1 wave = 16 q-rows ----------------
__global__ __launch_bounds__(256)
void attn_kernel(const u16* __restrict__ Q, const u16* __restrict__ K,
                 const u16* __restrict__ Vt, u16* __restrict__ O) {
  __shared__ __align__(16) u16 Ks[64 * 72];       // [key][feat], stride 72
  __shared__ __align__(16) u16 Vs[64 * 72];       // [feat][key], stride 72
  __shared__ __align__(16) u16 Ps[4][16 * 72];    // per-wave P [qrow][key]
  const int tid = threadIdx.x, wave = tid >> 6, lane = tid & 63;
  const int quad = lane >> 4, l16 = lane & 15;
  const int b = blockIdx.z, h = blockIdx.y, qt = blockIdx.x;
  const size_t bh = (size_t)(b * 16 + h);
  const u16* Qp = Q + bh * (2048 * 64);
  const u16* Kp = K + bh * (2048 * 64);
  const u16* Vp = Vt + bh * (64 * 2048);
  const int q0 = qt * 64 + wave * 16;
  const bf16x8 qf0 = *(const bf16x8*)&Qp[(size_t)(q0 + l16) * 64 + quad * 8];
  const bf16x8 qf1 = *(const bf16x8*)&Qp[(size_t)(q0 + l16) * 64 + 32 + quad * 8];
  float m_run[4] = {-1e30f, -1e30f, -1e30f, -1e30f};
  float l_run[4] = {0.f, 0.f, 0.f, 0.f};
  const f32x4 fz = {0.f, 0.f, 0.f, 0.f};
  f32x4 acc[4]; 
#pragma unroll
  for (int g = 0; g < 4; g++) acc[g] = fz;

  const int sr = tid >> 2;         // 0..63
  const int sc = (tid & 3) * 16;   // 0,16,32,48

  for (int t0 = 0; t0 < 2048; t0 += 64) {
    __syncthreads();
    { // stage K tile [64 keys][64 feats] and V^T tile [64 feats][64 keys]
      const u16* ksrc = &Kp[(size_t)(t0 + sr) * 64 + sc];
      u16* kdst = &Ks[sr * 72 + sc];
      *(bf16x8*)kdst = *(const bf16x8*)ksrc;
      *(bf16x8*)(kdst + 8) = *(const bf16x8*)(ksrc + 8);
      const u16* vsrc = &Vp[(size_t)sr * 2048 + t0 + sc];
      u16* vdst = &Vs[sr * 72 + sc];
      *(bf16x8*)vdst = *(const bf16x8*)vsrc;
      *(bf16x8*)(vdst + 8) = *(const bf16x8*)(vsrc + 8);
    }
    __syncthreads();
    // S = Q K^T for 16 q-rows x 64 keys (4 col-groups, K=64 chained)
    f32x4 sf[4];
#pragma unroll
    for (int g = 0; g < 4; g++) {
      const bf16x8 kb0 = *(const bf16x8*)&Ks[(g * 16 + l16) * 72 + quad * 8];
      const bf16x8 kb1 = *(const bf16x8*)&Ks[(g * 16 + l16) * 72 + 32 + quad * 8];
      f32x4 z = fz;
      z = __builtin_amdgcn_mfma_f32_16x16x32_bf16(qf0, kb0, z, 0, 0, 0);
      z = __builtin_amdgcn_mfma_f32_16x16x32_bf16(qf1, kb1, z, 0, 0, 0);
      sf[g] = z;
    }
    // online softmax per q-row (row = quad*4+r; 16 lanes of the quad hold the cols)
    u16* Pw = &Ps[wave][0];
#pragma unroll
    for (int r = 0; r < 4; r++) {
      float mx = fmaxf(fmaxf(sf[0][r], sf[1][r]), fmaxf(sf[2][r], sf[3][r]));
#pragma unroll
      for (int mm = 1; mm < 16; mm <<= 1) mx = fmaxf(mx, __shfl_xor(mx, mm));
      const float mn = fmaxf(m_run[r], mx);
      const float al = __expf(m_run[r] - mn);
      const float p0 = __expf(sf[0][r] - mn);
      const float p1 = __expf(sf[1][r] - mn);
      const float p2 = __expf(sf[2][r] - mn);
      const float p3 = __expf(sf[3][r] - mn);
      float sum = p0 + p1 + p2 + p3;
#pragma unroll
      for (int mm = 1; mm < 16; mm <<= 1) sum += __shfl_xor(sum, mm);
      m_run[r] = mn;
      l_run[r] = l_run[r] * al + sum;
      acc[0][r] *= al; acc[1][r] *= al; acc[2][r] *= al; acc[3][r] *= al;
      const int prow = (quad * 4 + r) * 72;
      Pw[prow + 0  + l16] = f2bf(p0);
      Pw[prow + 16 + l16] = f2bf(p1);
      Pw[prow + 32 + l16] = f2bf(p2);
      Pw[prow + 48 + l16] = f2bf(p3);
    }
    // P (A-layout via LDS round-trip) @ V
    const bf16x8 pa0 = *(const bf16x8*)&Pw[l16 * 72 + quad * 8];
    const bf16x8 pa1 = *(const bf16x8*)&Pw[l16 * 72 + 32 + quad * 8];
#pragma unroll
    for (int g = 0; g < 4; g++) {
      const bf16x8 vb0 = *(const bf16x8*)&Vs[(g * 16 + l16) * 72 + quad * 8];
      const bf16x8 vb1 = *(const bf16x8*)&Vs[(g * 16 + l16) * 72 + 32 + quad * 8];
      acc[g] = __builtin_amdgcn_mfma_f32_16x16x32_bf16(pa0, vb0, acc[g], 0, 0, 0);
      acc[g] = __builtin_amdgcn_mfma_f32_16x16x32_bf16(pa1, vb1, acc[g], 0, 0, 0);
    }
  }
#pragma unroll
  for (int r = 0; r < 4; r++) {
    const float inv = 1.0f / l_run[r];
    const int s = q0 + quad * 4 + r;
    const size_t base = ((size_t)(b * 2048 + s)) * 1024 + h * 64;
#pragma unroll
    for (int g = 0; g < 4; g++)
      O[base + g * 16 + l16] = f2bf(acc[g][r] * inv);
  }
}

// ---------------- launch ----------------
extern "C" void kernel_launch(void* const* d_in, const int* in_sizes, int n_in,
                              void* d_out, int out_size, void* d_ws, size_t ws_size,
                              hipStream_t stream) {
  const float* x   = (const float*)d_in[0];
  const float* Wq  = (const float*)d_in[1];
  const float* bq  = (const float*)d_in[2];
  const float* Wk  = (const float*)d_in[3];
  const float* bk  = (const float*)d_in[4];
  const float* Wv  = (const float*)d_in[5];
  const float* bv  = (const float*)d_in[6];
  const float* Wo  = (const float*)d_in[7];
  const float* bo  = (const float*)d_in[8];
  const float* g1  = (const float*)d_in[9];
  const float* be1 = (const float*)d_in[10];
  const float* W1  = (const float*)d_in[11];
  const float* b1  = (const float*)d_in[12];
  const float* W2  = (const float*)d_in[13];
  const float* b2  = (const float*)d_in[14];
  const float* g2  = (const float*)d_in[15];
  const float* be2 = (const float*)d_in[16];
  float* out = (float*)d_out;

  char* w = (char*)d_ws;
  u16* wqkv = (u16*)w; w += (size_t)3072 * 1024 * 2;
  u16* wob  = (u16*)w; w += (size_t)1024 * 1024 * 2;
  u16* w1b  = (u16*)w; w += (size_t)4096 * 1024 * 2;
  u16* w2b  = (u16*)w; w += (size_t)1024 * 4096 * 2;
  u16* hb   = (u16*)w; w += (size_t)4096 * 1024 * 2;
  u16* qb   = (u16*)w; w += (size_t)4096 * 1024 * 2;
  u16* kb   = (u16*)w; w += (size_t)4096 * 1024 * 2;
  u16* vtb  = (u16*)w; w += (size_t)4096 * 1024 * 2;
  u16* atb  = (u16*)w; w += (size_t)4096 * 1024 * 2;
  u16* m1b  = (u16*)w; w += (size_t)4096 * 4096 * 2;

  f2b_kernel<<<1024, 256, 0, stream>>>(Wq, wqkv, 262144);
  f2b_kernel<<<1024, 256, 0, stream>>>(Wk, wqkv + 1024 * 1024, 262144);
  f2b_kernel<<<1024, 256, 0, stream>>>(Wv, wqkv + 2 * 1024 * 1024, 262144);
  f2b_kernel<<<1024, 256, 0, stream>>>(Wo, wob, 262144);
  f2b_kernel<<<4096, 256, 0, stream>>>(W1, w1b, 1048576);
  f2b_kernel<<<4096, 256, 0, stream>>>(W2, w2b, 1048576);

  ln_kernel<<<4096, 256, 0, stream>>>(x, g1, be1, hb);
  gemm_bt<EpiQKV><<<dim3(32, 24), 256, 0, stream>>>(hb, wqkv, 1024,
      EpiQKV{qb, kb, vtb, bq, bk, bv});
  attn_kernel<<<dim3(32, 16, 2), 256, 0, stream>>>(qb, kb, vtb, atb);
  gemm_bt<EpiO><<<dim3(32, 8), 256, 0, stream>>>(atb, wob, 1024, EpiO{x, bo, out});
  ln_kernel<<<4096, 256, 0, stream>>>(out, g2, be2, hb);
  gemm_bt<EpiGelu><<<dim3(32, 32), 256, 0, stream>>>(hb, w1b, 1024, EpiGelu{b1, m1b});
  gemm_bt<EpiOut><<<dim3(32, 8), 256, 0, stream>>>(m1b, w2b, 4096, EpiOut{b2, out});
}

// Round 2
// 398.078 us; speedup vs baseline: 1.3382x; 1.3382x over previous
//
#include <hip/hip_runtime.h>

typedef unsigned short u16;
typedef __attribute__((ext_vector_type(8))) __bf16 bf16x8;
typedef __attribute__((ext_vector_type(4))) __bf16 bf16x4;
typedef __attribute__((ext_vector_type(4))) float f32x4;
typedef __attribute__((ext_vector_type(4))) unsigned short u16x4;

#define AS1 __attribute__((address_space(1)))
#define AS3 __attribute__((address_space(3)))

__device__ __forceinline__ void async_load16(const void* g, void* l) {
  __builtin_amdgcn_global_load_lds((const AS1 void*)g, (AS3 void*)l, 16, 0, 0);
}

__device__ __forceinline__ float exp2_fast(float x) {
#if __has_builtin(__builtin_amdgcn_exp2f)
  return __builtin_amdgcn_exp2f(x);
#else
  return exp2f(x);
#endif
}
__device__ __forceinline__ float rcp_fast(float x) {
#if __has_builtin(__builtin_amdgcn_rcpf)
  return __builtin_amdgcn_rcpf(x);
#else
  return 1.0f / x;
#endif
}

__device__ __forceinline__ u16 f2bf(float f) {   // manual RNE (ln / f2b paths)
  union { float f; unsigned u; } a; a.f = f;
  unsigned u = a.u;
  u += 0x7fffu + ((u >> 16) & 1u);
  return (u16)(u >> 16);
}
__device__ __forceinline__ u16 bf_bits(float f) {  // native cvt (RNE)
  union { __bf16 b; u16 u; } c; c.b = (__bf16)f; return c.u;
}

// ---------------- fp32 -> bf16 convert (weights) ----------------
__global__ __launch_bounds__(256)
void f2b_kernel(const float* __restrict__ s, u16* __restrict__ d, int n4) {
  int i = blockIdx.x * 256 + threadIdx.x;
  if (i >= n4) return;
  const float4 v = ((const float4*)s)[i];
  u16x4 o; o[0] = f2bf(v.x); o[1] = f2bf(v.y); o[2] = f2bf(v.z); o[3] = f2bf(v.w);
  ((u16x4*)d)[i] = o;
}

// ---------------- LayerNorm (1024 cols, 1 block/row) ----------------
__global__ __launch_bounds__(256)
void ln_kernel(const float* __restrict__ x, const float* __restrict__ g,
               const float* __restrict__ b, u16* __restrict__ out) {
  const int row = blockIdx.x, tid = threadIdx.x;
  const float4 v = ((const float4*)(x + (size_t)row * 1024))[tid];
  float s = v.x + v.y + v.z + v.w;
  float s2 = v.x * v.x + v.y * v.y + v.z * v.z + v.w * v.w;
#pragma unroll
  for (int o = 1; o < 64; o <<= 1) { s += __shfl_xor(s, o); s2 += __shfl_xor(s2, o); }
  __shared__ float red[8];
  const int wave = tid >> 6, lane = tid & 63;
  if (lane == 0) { red[wave] = s; red[wave + 4] = s2; }
  __syncthreads();
  s = red[0] + red[1] + red[2] + red[3];
  s2 = red[4] + red[5] + red[6] + red[7];
  const float mu = s * (1.f / 1024.f);
  const float rstd = rsqrtf(s2 * (1.f / 1024.f) - mu * mu + 1e-5f);
  const float4 gg = ((const float4*)g)[tid];
  const float4 bb = ((const float4*)b)[tid];
  u16x4 o4;
  o4[0] = f2bf((v.x - mu) * rstd * gg.x + bb.x);
  o4[1] = f2bf((v.y - mu) * rstd * gg.y + bb.y);
  o4[2] = f2bf((v.z - mu) * rstd * gg.z + bb.z);
  o4[3] = f2bf((v.w - mu) * rstd * gg.w + bb.w);
  ((u16x4*)(out + (size_t)row * 1024))[tid] = o4;
}

// ---------------- GEMM C = A * B^T, A[M,K] bf16, B[N,K] bf16 ----------------
// BM=128 fixed, BN in {64,128}. 4 waves 2x2; m97 structure (global_load_lds w=16).
template <int BN, class Epi>
__global__ __launch_bounds__(256)
void gemm_bt(const u16* __restrict__ A, const u16* __restrict__ Bw, int K, Epi epi) {
  constexpr int NT = BN / 32;     // mfma col-tiles per wave
  constexpr int BLB = BN / 64;    // B staging instrs per thread (1 or 2)
  __shared__ __align__(16) u16 As[128 * 32];
  __shared__ __align__(16) u16 Bs[BN * 32];
  const int tid = threadIdx.x;
  const int wave = tid >> 6, lane = tid & 63;
  const int quad = lane >> 4, l16 = lane & 15;
  const int bm = blockIdx.x * 128, bn = blockIdx.y * BN;
  const int wm = (wave & 1) * 64, wn = (wave >> 1) * (BN / 2);

  const int srow = lane >> 2, scol = (lane & 3) * 8;
  const u16* pa0 = A + (size_t)(bm + wave * 32 + srow) * K + scol;
  const u16* pa1 = pa0 + (size_t)16 * K;
  const u16* pb0 = Bw + (size_t)(bn + wave * 16 * BLB + srow) * K + scol;
  const u16* pb1 = pb0 + (size_t)16 * K;
  u16* la0 = &As[wave * 1024];
  u16* la1 = la0 + 512;
  u16* lb0 = &Bs[wave * 512 * BLB];
  u16* lb1 = lb0 + 512;

  const f32x4 fz = {0.f, 0.f, 0.f, 0.f};
  f32x4 acc[4][NT];
#pragma unroll
  for (int i = 0; i < 4; i++)
#pragma unroll
    for (int j = 0; j < NT; j++) acc[i][j] = fz;

  for (int k0 = 0; k0 < K; k0 += 32) {
    async_load16(pa0, la0);
    async_load16(pa1, la1);
    async_load16(pb0, lb0);
    if (BLB == 2) async_load16(pb1, lb1);
    pa0 += 32; pa1 += 32; pb0 += 32; pb1 += 32;
    __syncthreads();
    bf16x8 af[4], bfr[NT];
#pragma unroll
    for (int mi = 0; mi < 4; mi++)
      af[mi] = *(const bf16x8*)&As[(wm + mi * 16 + l16) * 32 + quad * 8];
#pragma unroll
    for (int ni = 0; ni < NT; ni++)
      bfr[ni] = *(const bf16x8*)&Bs[(wn + ni * 16 + l16) * 32 + quad * 8];
#pragma unroll
    for (int mi = 0; mi < 4; mi++)
#pragma unroll
      for (int ni = 0; ni < NT; ni++)
        acc[mi][ni] = __builtin_amdgcn_mfma_f32_16x16x32_bf16(af[mi], bfr[ni], acc[mi][ni], 0, 0, 0);
    __syncthreads();
  }
#pragma unroll
  for (int mi = 0; mi < 4; mi++)
#pragma unroll
    for (int ni = 0; ni < NT; ni++)
      epi(bm + wm + mi * 16 + quad * 4, bn + wn + ni * 16 + l16, acc[mi][ni]);
}

// ---------------- epilogues (rows m0..m0+3, col n) ----------------
struct EpiQKV {   // q[b,h,s,e] scaled by 0.125*log2(e); k[b,h,s,e]; v^T[b,h,e,s]
  u16 *q, *k, *vt; const float *bq, *bk, *bv;
  __device__ void operator()(int m0, int n, f32x4 v) const {
    const int which = n >> 10, nn = n & 1023;
    const int hh = nn >> 6, e = nn & 63;
    const int bb = m0 >> 11, s0 = m0 & 2047;
    const size_t bh = (size_t)(bb * 16 + hh);
    if (which == 0) {
      const float bias = bq[nn];
      u16* p = &q[(bh * 2048 + s0) * 64 + e];
#pragma unroll
      for (int r = 0; r < 4; r++) p[r * 64] = bf_bits((v[r] + bias) * 0.18033688f);
    } else if (which == 1) {
      const float bias = bk[nn];
      u16* p = &k[(bh * 2048 + s0) * 64 + e];
#pragma unroll
      for (int r = 0; r < 4; r++) p[r * 64] = bf_bits(v[r] + bias);
    } else {
      const float bias = bv[nn];
      bf16x4 pk;
#pragma unroll
      for (int r = 0; r < 4; r++) pk[r] = (__bf16)(v[r] + bias);
      *(bf16x4*)&vt[(bh * 64 + e) * 2048 + s0] = pk;   // 4 consecutive s -> b64
    }
  }
};
struct EpiO {     // out = x + attn@Wo^T + bo  (fp32)
  const float* x; const float* bo; float* out;
  __device__ void operator()(int m0, int n, f32x4 v) const {
    const float bias = bo[n];
#pragma unroll
    for (int r = 0; r < 4; r++) {
      const size_t i = (size_t)(m0 + r) * 1024 + n;
      out[i] = x[i] + v[r] + bias;
    }
  }
};
struct EpiGelu {  // gelu(u) = u * sigmoid(2*c*(u+0.044715u^3)) via exp2
  const float* b1; u16* o;
  __device__ void operator()(int m0, int n, f32x4 v) const {
    const float bias = b1[n];
#pragma unroll
    for (int r = 0; r < 4; r++) {
      const float u = v[r] + bias;
      const float z2 = u * (2.3021183f + 0.10294515f * u * u);  // 2*log2e*c*(1+0.044715u^2)
      const float d = 1.0f + exp2_fast(-z2);
      o[(size_t)(m0 + r) * 4096 + n] = bf_bits(u * rcp_fast(d));
    }
  }
};
struct EpiOut {   // out += mlp + b2 (out holds x1)
  const float* b2; float* out;
  __device__ void operator()(int m0, int n, f32x4 v) const {
    const float bias = b2[n];
#pragma unroll
    for (int r = 0; r < 4; r++) {
      const size_t i = (size_t)(m0 + r) * 1024 + n;
      out[i] += v[r] + bias;
    }
  }
};

// ---------------- flash attention, no-max softmax, 1 wave = 32 q-rows ----------------
// Q is pre-scaled by 0.125*log2(e): p = exp2(s). K rows staged permuted so that
// staged row r holds global key t0 + 4*(r&15) + (r>>4); then the S column (g,l16)
// corresponds to key offset p = 4*l16 + g, making each lane's 4 P-values contiguous
// (b64 store) while P reads / V-frag reads stay b128 with identity-staged V.
__global__ __launch_bounds__(256)
void attn_kernel(const u16* __restrict__ Q, const u16* __restrict__ K,
                 const u16* __restrict__ Vt, u16* __restrict__ O) {
  __shared__ __align__(16) u16 Ks[64 * 72];
  __shared__ __align__(16) u16 Vs[64 * 72];
  __shared__ __align__(16) u16 Ps[4][32 * 72];
  const int tid = threadIdx.x, wave = tid >> 6, lane = tid & 63;
  const int quad = lane >> 4, l16 = lane & 15;
  const int b = blockIdx.z, h = blockIdx.y, qt = blockIdx.x;
  const size_t bh = (size_t)(b * 16 + h);
  const u16* Qp = Q + bh * (size_t)(2048 * 64);
  const u16* Kp = K + bh * (size_t)(2048 * 64);
  const u16* Vp = Vt + bh * (size_t)(64 * 2048);
  const int q0 = qt * 128 + wave * 32;

  bf16x8 qf[2][2];
#pragma unroll
  for (int rg = 0; rg < 2; rg++) {
    const u16* qrow = &Qp[(size_t)(q0 + rg * 16 + l16) * 64 + quad * 8];
    qf[rg][0] = *(const bf16x8*)qrow;
    qf[rg][1] = *(const bf16x8*)(qrow + 32);
  }

  const int sr = tid >> 2, sc = (tid & 3) * 16;
  const int krow = 4 * (sr & 15) + (sr >> 4);          // permuted key row
  const u16* kg = &Kp[(size_t)krow * 64 + sc];
  const u16* vg = &Vp[(size_t)sr * 2048 + sc];
  u16* kl = &Ks[sr * 72 + sc];
  u16* vl = &Vs[sr * 72 + sc];
  u16* Pw = &Ps[wave][0];

  bf16x8 ones;
#pragma unroll
  for (int i = 0; i < 8; i++) ones[i] = (__bf16)1.0f;

  const f32x4 fz = {0.f, 0.f, 0.f, 0.f};
  f32x4 acc[2][4], lsum[2];
#pragma unroll
  for (int rg = 0; rg < 2; rg++) {
    lsum[rg] = fz;
#pragma unroll
    for (int g = 0; g < 4; g++) acc[rg][g] = fz;
  }

  // register prefetch of tile 0
  bf16x8 pk0 = *(const bf16x8*)kg, pk1 = *(const bf16x8*)(kg + 8);
  bf16x8 pv0 = *(const bf16x8*)vg, pv1 = *(const bf16x8*)(vg + 8);

  for (int t0 = 0; t0 < 2048; t0 += 64) {
    *(bf16x8*)kl = pk0; *(bf16x8*)(kl + 8) = pk1;
    *(bf16x8*)vl = pv0; *(bf16x8*)(vl + 8) = pv1;
    __syncthreads();
    // prefetch next tile (last iter reads spill 16B into the next ws buffer; unused)
    kg += 64 * 64; vg += 64;
    pk0 = *(const bf16x8*)kg; pk1 = *(const bf16x8*)(kg + 8);
    pv0 = *(const bf16x8*)vg; pv1 = *(const bf16x8*)(vg + 8);

    // S = Q K^T (columns in permuted key order)
    f32x4 s[2][4];
#pragma unroll
    for (int g = 0; g < 4; g++) {
      const u16* kr = &Ks[(g * 16 + l16) * 72 + quad * 8];
      const bf16x8 kb0 = *(const bf16x8*)kr;
      const bf16x8 kb1 = *(const bf16x8*)(kr + 32);
#pragma unroll
      for (int rg = 0; rg < 2; rg++) {
        f32x4 z = __builtin_amdgcn_mfma_f32_16x16x32_bf16(qf[rg][0], kb0, fz, 0, 0, 0);
        s[rg][g] = __builtin_amdgcn_mfma_f32_16x16x32_bf16(qf[rg][1], kb1, z, 0, 0, 0);
      }
    }
    // p = exp2(s); packed b64 store into per-wave P (phys col = 4*l16+g = key offset)
#pragma unroll
    for (int rg = 0; rg < 2; rg++)
#pragma unroll
      for (int r = 0; r < 4; r++) {
        f32x4 pf;
#pragma unroll
        for (int g = 0; g < 4; g++) pf[g] = exp2_fast(s[rg][g][r]);
        const bf16x4 pb = __builtin_convertvector(pf, bf16x4);
        *(bf16x4*)&Pw[(rg * 16 + quad * 4 + r) * 72 + 4 * l16] = pb;
      }
    // P A-frags; row sums via ones-MFMA; PV
    bf16x8 pa[2][2];
#pragma unroll
    for (int rg = 0; rg < 2; rg++) {
      const u16* pr = &Pw[(rg * 16 + l16) * 72 + quad * 8];
      pa[rg][0] = *(const bf16x8*)pr;
      pa[rg][1] = *(const bf16x8*)(pr + 32);
      lsum[rg] = __builtin_amdgcn_mfma_f32_16x16x32_bf16(pa[rg][0], ones, lsum[rg], 0, 0, 0);
      lsum[rg] = __builtin_amdgcn_mfma_f32_16x16x32_bf16(pa[rg][1], ones, lsum[rg], 0, 0, 0);
    }
#pragma unroll
    for (int g = 0; g < 4; g++) {
      const u16* vr = &Vs[(g * 16 + l16) * 72 + quad * 8];
      const bf16x8 vb0 = *(const bf16x8*)vr;
      const bf16x8 vb1 = *(const bf16x8*)(vr + 32);
#pragma unroll
      for (int rg = 0; rg < 2; rg++) {
        acc[rg][g] = __builtin_amdgcn_mfma_f32_16x16x32_bf16(pa[rg][0], vb0, acc[rg][g], 0, 0, 0);
        acc[rg][g] = __builtin_amdgcn_mfma_f32_16x16x32_bf16(pa[rg][1], vb1, acc[rg][g], 0, 0, 0);
      }
    }
    __syncthreads();
  }
  // O[b, s, h*64+e] = acc / lsum
#pragma unroll
  for (int rg = 0; rg < 2; rg++)
#pragma unroll
    for (int r = 0; r < 4; r++) {
      const float inv = rcp_fast(lsum[rg][r]);
      const int s_row = q0 + rg * 16 + quad * 4 + r;
      u16* op = (u16*)&O[((size_t)(b * 2048 + s_row)) * 1024 + h * 64 + l16];
#pragma unroll
      for (int g = 0; g < 4; g++) op[g * 16] = bf_bits(acc[rg][g][r] * inv);
    }
}

// ---------------- launch ----------------
extern "C" void kernel_launch(void* const* d_in, const int* in_sizes, int n_in,
                              void* d_out, int out_size, void* d_ws, size_t ws_size,
                              hipStream_t stream) {
  const float* x   = (const float*)d_in[0];
  const float* Wq  = (const float*)d_in[1];
  const float* bq  = (const float*)d_in[2];
  const float* Wk  = (const float*)d_in[3];
  const float* bk  = (const float*)d_in[4];
  const float* Wv  = (const float*)d_in[5];
  const float* bv  = (const float*)d_in[6];
  const float* Wo  = (const float*)d_in[7];
  const float* bo  = (const float*)d_in[8];
  const float* g1  = (const float*)d_in[9];
  const float* be1 = (const float*)d_in[10];
  const float* W1  = (const float*)d_in[11];
  const float* b1  = (const float*)d_in[12];
  const float* W2  = (const float*)d_in[13];
  const float* b2  = (const float*)d_in[14];
  const float* g2  = (const float*)d_in[15];
  const float* be2 = (const float*)d_in[16];
  float* out = (float*)d_out;

  char* w = (char*)d_ws;
  u16* wqkv = (u16*)w; w += (size_t)3072 * 1024 * 2;
  u16* wob  = (u16*)w; w += (size_t)1024 * 1024 * 2;
  u16* w1b  = (u16*)w; w += (size_t)4096 * 1024 * 2;
  u16* w2b  = (u16*)w; w += (size_t)1024 * 4096 * 2;
  u16* hb   = (u16*)w; w += (size_t)4096 * 1024 * 2;
  u16* qb   = (u16*)w; w += (size_t)4096 * 1024 * 2;
  u16* kb   = (u16*)w; w += (size_t)4096 * 1024 * 2;
  u16* vtb  = (u16*)w; w += (size_t)4096 * 1024 * 2;
  u16* atb  = (u16*)w; w += (size_t)4096 * 1024 * 2;
  u16* m1b  = (u16*)w; w += (size_t)4096 * 4096 * 2;

  f2b_kernel<<<1024, 256, 0, stream>>>(Wq, wqkv, 262144);
  f2b_kernel<<<1024, 256, 0, stream>>>(Wk, wqkv + 1024 * 1024, 262144);
  f2b_kernel<<<1024, 256, 0, stream>>>(Wv, wqkv + 2 * 1024 * 1024, 262144);
  f2b_kernel<<<1024, 256, 0, stream>>>(Wo, wob, 262144);
  f2b_kernel<<<4096, 256, 0, stream>>>(W1, w1b, 1048576);
  f2b_kernel<<<4096, 256, 0, stream>>>(W2, w2b, 1048576);

  ln_kernel<<<4096, 256, 0, stream>>>(x, g1, be1, hb);
  gemm_bt<128, EpiQKV><<<dim3(32, 24), 256, 0, stream>>>(hb, wqkv, 1024,
      EpiQKV{qb, kb, vtb, bq, bk, bv});
  attn_kernel<<<dim3(16, 16, 2), 256, 0, stream>>>(qb, kb, vtb, atb);
  gemm_bt<64, EpiO><<<dim3(32, 16), 256, 0, stream>>>(atb, wob, 1024, EpiO{x, bo, out});
  ln_kernel<<<4096, 256, 0, stream>>>(out, g2, be2, hb);
  gemm_bt<128, EpiGelu><<<dim3(32, 32), 256, 0, stream>>>(hb, w1b, 1024, EpiGelu{b1, m1b});
  gemm_bt<64, EpiOut><<<dim3(32, 16), 256, 0, stream>>>(m1b, w2b, 4096, EpiOut{b2, out});
}

// Round 4
// 391.894 us; speedup vs baseline: 1.3593x; 1.0158x over previous
//
#include <hip/hip_runtime.h>

typedef unsigned short u16;
typedef __attribute__((ext_vector_type(8))) __bf16 bf16x8;
typedef __attribute__((ext_vector_type(4))) __bf16 bf16x4;
typedef __attribute__((ext_vector_type(4))) float f32x4;
typedef __attribute__((ext_vector_type(4))) unsigned short u16x4;

#define AS1 __attribute__((address_space(1)))
#define AS3 __attribute__((address_space(3)))

__device__ __forceinline__ void async_load16(const void* g, void* l) {
  __builtin_amdgcn_global_load_lds((const AS1 void*)g, (AS3 void*)l, 16, 0, 0);
}

__device__ __forceinline__ float exp2_fast(float x) {
#if __has_builtin(__builtin_amdgcn_exp2f)
  return __builtin_amdgcn_exp2f(x);
#else
  return exp2f(x);
#endif
}
__device__ __forceinline__ float rcp_fast(float x) {
#if __has_builtin(__builtin_amdgcn_rcpf)
  return __builtin_amdgcn_rcpf(x);
#else
  return 1.0f / x;
#endif
}

__device__ __forceinline__ u16 f2bf(float f) {   // manual RNE
  union { float f; unsigned u; } a; a.f = f;
  unsigned u = a.u;
  u += 0x7fffu + ((u >> 16) & 1u);
  return (u16)(u >> 16);
}
__device__ __forceinline__ u16 bf_bits(float f) {  // native cvt (RNE)
  union { __bf16 b; u16 u; } c; c.b = (__bf16)f; return c.u;
}

// ---------------- fp32 -> bf16 convert (weights) ----------------
__global__ __launch_bounds__(256)
void f2b_kernel(const float* __restrict__ s, u16* __restrict__ d, int n4) {
  int i = blockIdx.x * 256 + threadIdx.x;
  if (i >= n4) return;
  const float4 v = ((const float4*)s)[i];
  u16x4 o; o[0] = f2bf(v.x); o[1] = f2bf(v.y); o[2] = f2bf(v.z); o[3] = f2bf(v.w);
  ((u16x4*)d)[i] = o;
}

// ---------------- LayerNorm (1024 cols, 1 block/row) ----------------
__global__ __launch_bounds__(256)
void ln_kernel(const float* __restrict__ x, const float* __restrict__ g,
               const float* __restrict__ b, u16* __restrict__ out) {
  const int row = blockIdx.x, tid = threadIdx.x;
  const float4 v = ((const float4*)(x + (size_t)row * 1024))[tid];
  float s = v.x + v.y + v.z + v.w;
  float s2 = v.x * v.x + v.y * v.y + v.z * v.z + v.w * v.w;
#pragma unroll
  for (int o = 1; o < 64; o <<= 1) { s += __shfl_xor(s, o); s2 += __shfl_xor(s2, o); }
  __shared__ float red[8];
  const int wave = tid >> 6, lane = tid & 63;
  if (lane == 0) { red[wave] = s; red[wave + 4] = s2; }
  __syncthreads();
  s = red[0] + red[1] + red[2] + red[3];
  s2 = red[4] + red[5] + red[6] + red[7];
  const float mu = s * (1.f / 1024.f);
  const float rstd = rsqrtf(s2 * (1.f / 1024.f) - mu * mu + 1e-5f);
  const float4 gg = ((const float4*)g)[tid];
  const float4 bb = ((const float4*)b)[tid];
  u16x4 o4;
  o4[0] = f2bf((v.x - mu) * rstd * gg.x + bb.x);
  o4[1] = f2bf((v.y - mu) * rstd * gg.y + bb.y);
  o4[2] = f2bf((v.z - mu) * rstd * gg.z + bb.z);
  o4[3] = f2bf((v.w - mu) * rstd * gg.w + bb.w);
  ((u16x4*)(out + (size_t)row * 1024))[tid] = o4;
}

// ------- fused: out = x + p0 + p1 + bo ; hb = LN(out; g,b) (1 block/row) -------
__global__ __launch_bounds__(256)
void ln_fuse(const float* __restrict__ x, const float* __restrict__ p0,
             const float* __restrict__ p1, const float* __restrict__ bo,
             const float* __restrict__ g, const float* __restrict__ b,
             float* __restrict__ out, u16* __restrict__ hb) {
  const int row = blockIdx.x, tid = threadIdx.x;
  const size_t base = (size_t)row * 1024;
  const float4 xv = ((const float4*)(x + base))[tid];
  const float4 a0 = ((const float4*)(p0 + base))[tid];
  const float4 a1 = ((const float4*)(p1 + base))[tid];
  const float4 bv = ((const float4*)bo)[tid];
  float4 t;
  t.x = xv.x + a0.x + a1.x + bv.x;
  t.y = xv.y + a0.y + a1.y + bv.y;
  t.z = xv.z + a0.z + a1.z + bv.z;
  t.w = xv.w + a0.w + a1.w + bv.w;
  ((float4*)(out + base))[tid] = t;
  float s = t.x + t.y + t.z + t.w;
  float s2 = t.x * t.x + t.y * t.y + t.z * t.z + t.w * t.w;
#pragma unroll
  for (int o = 1; o < 64; o <<= 1) { s += __shfl_xor(s, o); s2 += __shfl_xor(s2, o); }
  __shared__ float red[8];
  const int wave = tid >> 6, lane = tid & 63;
  if (lane == 0) { red[wave] = s; red[wave + 4] = s2; }
  __syncthreads();
  s = red[0] + red[1] + red[2] + red[3];
  s2 = red[4] + red[5] + red[6] + red[7];
  const float mu = s * (1.f / 1024.f);
  const float rstd = rsqrtf(s2 * (1.f / 1024.f) - mu * mu + 1e-5f);
  const float4 gg = ((const float4*)g)[tid];
  const float4 bb = ((const float4*)b)[tid];
  u16x4 o4;
  o4[0] = f2bf((t.x - mu) * rstd * gg.x + bb.x);
  o4[1] = f2bf((t.y - mu) * rstd * gg.y + bb.y);
  o4[2] = f2bf((t.z - mu) * rstd * gg.z + bb.z);
  o4[3] = f2bf((t.w - mu) * rstd * gg.w + bb.w);
  ((u16x4*)(hb + base))[tid] = o4;
}

// ------------- out += m0 + m1 + b2 (final MLP2 reduction) -------------
__global__ __launch_bounds__(256)
void add2(float* __restrict__ out, const float* __restrict__ m0,
          const float* __restrict__ m1, const float* __restrict__ b2) {
  const int i = blockIdx.x * 256 + threadIdx.x;
  const float4 o = ((const float4*)out)[i];
  const float4 a = ((const float4*)m0)[i];
  const float4 c = ((const float4*)m1)[i];
  const float4 bv = ((const float4*)b2)[i & 255];
  float4 r;
  r.x = o.x + a.x + c.x + bv.x;
  r.y = o.y + a.y + c.y + bv.y;
  r.z = o.z + a.z + c.z + bv.z;
  r.w = o.w + a.w + c.w + bv.w;
  ((float4*)out)[i] = r;
}

// ---------------- GEMM C = A * B^T, A[M,ldk] bf16, B[N,ldk] bf16 ----------------
// BM=128, BN=128. 4 waves 2x2; m97 structure. blockIdx.z = split-K slice (len K).
template <class Epi>
__global__ __launch_bounds__(256)
void gemm_bt(const u16* __restrict__ A, const u16* __restrict__ Bw,
             int ldk, int K, Epi epi) {
  __shared__ __align__(16) u16 As[128 * 32];
  __shared__ __align__(16) u16 Bs[128 * 32];
  const int tid = threadIdx.x;
  const int wave = tid >> 6, lane = tid & 63;
  const int quad = lane >> 4, l16 = lane & 15;
  const int bm = blockIdx.x * 128, bn = blockIdx.y * 128;
  const int kz = blockIdx.z;
  const int wm = (wave & 1) * 64, wn = (wave >> 1) * 64;

  const int srow = lane >> 2, scol = (lane & 3) * 8;
  const u16* pa0 = A + (size_t)(bm + wave * 32 + srow) * ldk + (size_t)kz * K + scol;
  const u16* pa1 = pa0 + (size_t)16 * ldk;
  const u16* pb0 = Bw + (size_t)(bn + wave * 32 + srow) * ldk + (size_t)kz * K + scol;
  const u16* pb1 = pb0 + (size_t)16 * ldk;
  u16* la0 = &As[wave * 1024];
  u16* la1 = la0 + 512;
  u16* lb0 = &Bs[wave * 1024];
  u16* lb1 = lb0 + 512;

  const f32x4 fz = {0.f, 0.f, 0.f, 0.f};
  f32x4 acc[4][4];
#pragma unroll
  for (int i = 0; i < 4; i++)
#pragma unroll
    for (int j = 0; j < 4; j++) acc[i][j] = fz;

  for (int k0 = 0; k0 < K; k0 += 32) {
    async_load16(pa0, la0);
    async_load16(pa1, la1);
    async_load16(pb0, lb0);
    async_load16(pb1, lb1);
    pa0 += 32; pa1 += 32; pb0 += 32; pb1 += 32;
    __syncthreads();
    bf16x8 af[4], bfr[4];
#pragma unroll
    for (int mi = 0; mi < 4; mi++)
      af[mi] = *(const bf16x8*)&As[(wm + mi * 16 + l16) * 32 + quad * 8];
#pragma unroll
    for (int ni = 0; ni < 4; ni++)
      bfr[ni] = *(const bf16x8*)&Bs[(wn + ni * 16 + l16) * 32 + quad * 8];
#pragma unroll
    for (int mi = 0; mi < 4; mi++)
#pragma unroll
      for (int ni = 0; ni < 4; ni++)
        acc[mi][ni] = __builtin_amdgcn_mfma_f32_16x16x32_bf16(af[mi], bfr[ni], acc[mi][ni], 0, 0, 0);
    __syncthreads();
  }
#pragma unroll
  for (int mi = 0; mi < 4; mi++)
#pragma unroll
    for (int ni = 0; ni < 4; ni++)
      epi(bm + wm + mi * 16 + quad * 4, bn + wn + ni * 16 + l16, kz, acc[mi][ni]);
}

// ---------------- epilogues (rows m0..m0+3, col n) ----------------
struct EpiQKV {   // q[b,h,s,e] scaled by 0.125*log2(e); k[b,h,s,e]; v^T[b,h,e,s]
  u16 *q, *k, *vt; const float *bq, *bk, *bv;
  __device__ void operator()(int m0, int n, int, f32x4 v) const {
    const int which = n >> 10, nn = n & 1023;
    const int hh = nn >> 6, e = nn & 63;
    const int bb = m0 >> 11, s0 = m0 & 2047;
    const size_t bh = (size_t)(bb * 16 + hh);
    if (which == 0) {
      const float bias = bq[nn];
      u16* p = &q[(bh * 2048 + s0) * 64 + e];
#pragma unroll
      for (int r = 0; r < 4; r++) p[r * 64] = bf_bits((v[r] + bias) * 0.18033688f);
    } else if (which == 1) {
      const float bias = bk[nn];
      u16* p = &k[(bh * 2048 + s0) * 64 + e];
#pragma unroll
      for (int r = 0; r < 4; r++) p[r * 64] = bf_bits(v[r] + bias);
    } else {
      const float bias = bv[nn];
      bf16x4 pk;
#pragma unroll
      for (int r = 0; r < 4; r++) pk[r] = (__bf16)(v[r] + bias);
      *(bf16x4*)&vt[(bh * 64 + e) * 2048 + s0] = pk;
    }
  }
};
struct EpiPart {  // raw split-K partial -> p[kz] (fp32, [4096,1024])
  float *p0, *p1;
  __device__ void operator()(int m0, int n, int kz, f32x4 v) const {
    float* p = kz ? p1 : p0;
#pragma unroll
    for (int r = 0; r < 4; r++) p[(size_t)(m0 + r) * 1024 + n] = v[r];
  }
};
struct EpiGelu {  // gelu(u) = u * sigmoid(2*c*(u+0.044715u^3)) via exp2
  const float* b1; u16* o;
  __device__ void operator()(int m0, int n, int, f32x4 v) const {
    const float bias = b1[n];
#pragma unroll
    for (int r = 0; r < 4; r++) {
      const float u = v[r] + bias;
      const float z2 = u * (2.3021183f + 0.10294515f * u * u);
      const float d = 1.0f + exp2_fast(-z2);
      o[(size_t)(m0 + r) * 4096 + n] = bf_bits(u * rcp_fast(d));
    }
  }
};

// ---------------- flash attention, no-max softmax, 1 wave = 32 q-rows ----------------
__global__ __launch_bounds__(256)
void attn_kernel(const u16* __restrict__ Q, const u16* __restrict__ K,
                 const u16* __restrict__ Vt, u16* __restrict__ O) {
  __shared__ __align__(16) u16 Ks[64 * 72];
  __shared__ __align__(16) u16 Vs[64 * 72];
  __shared__ __align__(16) u16 Ps[4][32 * 72];
  const int tid = threadIdx.x, wave = tid >> 6, lane = tid & 63;
  const int quad = lane >> 4, l16 = lane & 15;
  const int b = blockIdx.z, h = blockIdx.y, qt = blockIdx.x;
  const size_t bh = (size_t)(b * 16 + h);
  const u16* Qp = Q + bh * (size_t)(2048 * 64);
  const u16* Kp = K + bh * (size_t)(2048 * 64);
  const u16* Vp = Vt + bh * (size_t)(64 * 2048);
  const int q0 = qt * 128 + wave * 32;

  bf16x8 qf[2][2];
#pragma unroll
  for (int rg = 0; rg < 2; rg++) {
    const u16* qrow = &Qp[(size_t)(q0 + rg * 16 + l16) * 64 + quad * 8];
    qf[rg][0] = *(const bf16x8*)qrow;
    qf[rg][1] = *(const bf16x8*)(qrow + 32);
  }

  const int sr = tid >> 2, sc = (tid & 3) * 16;
  const int krow = 4 * (sr & 15) + (sr >> 4);          // permuted key row
  const u16* kg = &Kp[(size_t)krow * 64 + sc];
  const u16* vg = &Vp[(size_t)sr * 2048 + sc];
  u16* kl = &Ks[sr * 72 + sc];
  u16* vl = &Vs[sr * 72 + sc];
  u16* Pw = &Ps[wave][0];

  bf16x8 ones;
#pragma unroll
  for (int i = 0; i < 8; i++) ones[i] = (__bf16)1.0f;

  const f32x4 fz = {0.f, 0.f, 0.f, 0.f};
  f32x4 acc[2][4], lsum[2];
#pragma unroll
  for (int rg = 0; rg < 2; rg++) {
    lsum[rg] = fz;
#pragma unroll
    for (int g = 0; g < 4; g++) acc[rg][g] = fz;
  }

  bf16x8 pk0 = *(const bf16x8*)kg, pk1 = *(const bf16x8*)(kg + 8);
  bf16x8 pv0 = *(const bf16x8*)vg, pv1 = *(const bf16x8*)(vg + 8);

  for (int t0 = 0; t0 < 2048; t0 += 64) {
    *(bf16x8*)kl = pk0; *(bf16x8*)(kl + 8) = pk1;
    *(bf16x8*)vl = pv0; *(bf16x8*)(vl + 8) = pv1;
    __syncthreads();
    kg += 64 * 64; vg += 64;
    pk0 = *(const bf16x8*)kg; pk1 = *(const bf16x8*)(kg + 8);
    pv0 = *(const bf16x8*)vg; pv1 = *(const bf16x8*)(vg + 8);

    f32x4 s[2][4];
#pragma unroll
    for (int g = 0; g < 4; g++) {
      const u16* kr = &Ks[(g * 16 + l16) * 72 + quad * 8];
      const bf16x8 kb0 = *(const bf16x8*)kr;
      const bf16x8 kb1 = *(const bf16x8*)(kr + 32);
#pragma unroll
      for (int rg = 0; rg < 2; rg++) {
        f32x4 z = __builtin_amdgcn_mfma_f32_16x16x32_bf16(qf[rg][0], kb0, fz, 0, 0, 0);
        s[rg][g] = __builtin_amdgcn_mfma_f32_16x16x32_bf16(qf[rg][1], kb1, z, 0, 0, 0);
      }
    }
#pragma unroll
    for (int rg = 0; rg < 2; rg++)
#pragma unroll
      for (int r = 0; r < 4; r++) {
        f32x4 pf;
#pragma unroll
        for (int g = 0; g < 4; g++) pf[g] = exp2_fast(s[rg][g][r]);
        const bf16x4 pb = __builtin_convertvector(pf, bf16x4);
        *(bf16x4*)&Pw[(rg * 16 + quad * 4 + r) * 72 + 4 * l16] = pb;
      }
    bf16x8 pa[2][2];
#pragma unroll
    for (int rg = 0; rg < 2; rg++) {
      const u16* pr = &Pw[(rg * 16 + l16) * 72 + quad * 8];
      pa[rg][0] = *(const bf16x8*)pr;
      pa[rg][1] = *(const bf16x8*)(pr + 32);
      lsum[rg] = __builtin_amdgcn_mfma_f32_16x16x32_bf16(pa[rg][0], ones, lsum[rg], 0, 0, 0);
      lsum[rg] = __builtin_amdgcn_mfma_f32_16x16x32_bf16(pa[rg][1], ones, lsum[rg], 0, 0, 0);
    }
#pragma unroll
    for (int g = 0; g < 4; g++) {
      const u16* vr = &Vs[(g * 16 + l16) * 72 + quad * 8];
      const bf16x8 vb0 = *(const bf16x8*)vr;
      const bf16x8 vb1 = *(const bf16x8*)(vr + 32);
#pragma unroll
      for (int rg = 0; rg < 2; rg++) {
        acc[rg][g] = __builtin_amdgcn_mfma_f32_16x16x32_bf16(pa[rg][0], vb0, acc[rg][g], 0, 0, 0);
        acc[rg][g] = __builtin_amdgcn_mfma_f32_16x16x32_bf16(pa[rg][1], vb1, acc[rg][g], 0, 0, 0);
      }
    }
    __syncthreads();
  }
#pragma unroll
  for (int rg = 0; rg < 2; rg++)
#pragma unroll
    for (int r = 0; r < 4; r++) {
      const float inv = rcp_fast(lsum[rg][r]);
      const int s_row = q0 + rg * 16 + quad * 4 + r;
      u16* op = (u16*)&O[((size_t)(b * 2048 + s_row)) * 1024 + h * 64 + l16];
#pragma unroll
      for (int g = 0; g < 4; g++) op[g * 16] = bf_bits(acc[rg][g][r] * inv);
    }
}

// ---------------- launch ----------------
extern "C" void kernel_launch(void* const* d_in, const int* in_sizes, int n_in,
                              void* d_out, int out_size, void* d_ws, size_t ws_size,
                              hipStream_t stream) {
  const float* x   = (const float*)d_in[0];
  const float* Wq  = (const float*)d_in[1];
  const float* bq  = (const float*)d_in[2];
  const float* Wk  = (const float*)d_in[3];
  const float* bk  = (const float*)d_in[4];
  const float* Wv  = (const float*)d_in[5];
  const float* bv  = (const float*)d_in[6];
  const float* Wo  = (const float*)d_in[7];
  const float* bo  = (const float*)d_in[8];
  const float* g1  = (const float*)d_in[9];
  const float* be1 = (const float*)d_in[10];
  const float* W1  = (const float*)d_in[11];
  const float* b1  = (const float*)d_in[12];
  const float* W2  = (const float*)d_in[13];
  const float* b2  = (const float*)d_in[14];
  const float* g2  = (const float*)d_in[15];
  const float* be2 = (const float*)d_in[16];
  float* out = (float*)d_out;

  char* w = (char*)d_ws;
  u16* wqkv = (u16*)w; w += (size_t)3072 * 1024 * 2;
  u16* wob  = (u16*)w; w += (size_t)1024 * 1024 * 2;
  u16* w1b  = (u16*)w; w += (size_t)4096 * 1024 * 2;
  u16* w2b  = (u16*)w; w += (size_t)1024 * 4096 * 2;
  u16* hb   = (u16*)w; w += (size_t)4096 * 1024 * 2;
  u16* qb   = (u16*)w; w += (size_t)4096 * 1024 * 2;   // later: m0 (fp32, spans qb+kb)
  u16* kb   = (u16*)w; w += (size_t)4096 * 1024 * 2;
  u16* vtb  = (u16*)w; w += (size_t)4096 * 1024 * 2;   // later: m1 (fp32, spans vtb+atb)
  u16* atb  = (u16*)w; w += (size_t)4096 * 1024 * 2;
  u16* m1b  = (u16*)w; w += (size_t)4096 * 4096 * 2;   // O-proj partials p0/p1 live here first

  float* p0 = (float*)m1b;                      // [4096,1024] fp32, dead before MLP1
  float* p1 = (float*)(m1b + 4096 * 2048);      // second 16MB of m1b
  float* m0 = (float*)qb;                       // qb+kb dead after ln_fuse
  float* m1 = (float*)vtb;                      // vtb+atb dead after O-proj

  f2b_kernel<<<1024, 256, 0, stream>>>(Wq, wqkv, 262144);
  f2b_kernel<<<1024, 256, 0, stream>>>(Wk, wqkv + 1024 * 1024, 262144);
  f2b_kernel<<<1024, 256, 0, stream>>>(Wv, wqkv + 2 * 1024 * 1024, 262144);
  f2b_kernel<<<1024, 256, 0, stream>>>(Wo, wob, 262144);
  f2b_kernel<<<4096, 256, 0, stream>>>(W1, w1b, 1048576);
  f2b_kernel<<<4096, 256, 0, stream>>>(W2, w2b, 1048576);

  ln_kernel<<<4096, 256, 0, stream>>>(x, g1, be1, hb);
  gemm_bt<EpiQKV><<<dim3(32, 24, 1), 256, 0, stream>>>(hb, wqkv, 1024, 1024,
      EpiQKV{qb, kb, vtb, bq, bk, bv});
  attn_kernel<<<dim3(16, 16, 2), 256, 0, stream>>>(qb, kb, vtb, atb);
  gemm_bt<EpiPart><<<dim3(32, 8, 2), 256, 0, stream>>>(atb, wob, 1024, 512,
      EpiPart{p0, p1});
  ln_fuse<<<4096, 256, 0, stream>>>(x, p0, p1, bo, g2, be2, out, hb);
  gemm_bt<EpiGelu><<<dim3(32, 32, 1), 256, 0, stream>>>(hb, w1b, 1024, 1024,
      EpiGelu{b1, m1b});
  gemm_bt<EpiPart><<<dim3(32, 8, 2), 256, 0, stream>>>(m1b, w2b, 4096, 2048,
      EpiPart{m0, m1});
  add2<<<4096, 256, 0, stream>>>(out, m0, m1, b2);
}

// Round 5
// 385.586 us; speedup vs baseline: 1.3816x; 1.0164x over previous
//
#include <hip/hip_runtime.h>

typedef unsigned short u16;
typedef __attribute__((ext_vector_type(8))) __bf16 bf16x8;
typedef __attribute__((ext_vector_type(4))) __bf16 bf16x4;
typedef __attribute__((ext_vector_type(4))) float f32x4;
typedef __attribute__((ext_vector_type(4))) unsigned short u16x4;

#define AS1 __attribute__((address_space(1)))
#define AS3 __attribute__((address_space(3)))

__device__ __forceinline__ void async_load16(const void* g, void* l) {
  __builtin_amdgcn_global_load_lds((const AS1 void*)g, (AS3 void*)l, 16, 0, 0);
}

__device__ __forceinline__ float exp2_fast(float x) {
#if __has_builtin(__builtin_amdgcn_exp2f)
  return __builtin_amdgcn_exp2f(x);
#else
  return exp2f(x);
#endif
}
__device__ __forceinline__ float rcp_fast(float x) {
#if __has_builtin(__builtin_amdgcn_rcpf)
  return __builtin_amdgcn_rcpf(x);
#else
  return 1.0f / x;
#endif
}

__device__ __forceinline__ u16 f2bf(float f) {   // manual RNE
  union { float f; unsigned u; } a; a.f = f;
  unsigned u = a.u;
  u += 0x7fffu + ((u >> 16) & 1u);
  return (u16)(u >> 16);
}
__device__ __forceinline__ u16 bf_bits(float f) {  // native cvt (RNE)
  union { __bf16 b; u16 u; } c; c.b = (__bf16)f; return c.u;
}
__device__ __forceinline__ float bf2f(u16 h) {
  union { unsigned u; float f; } c; c.u = ((unsigned)h) << 16; return c.f;
}

// ------- fp32 -> bf16: all 6 weights in ONE launch (dst contiguous in ws) -------
// f4 segment bounds: Wq 262144 | Wk 262144 | Wv 262144 | Wo 262144 | W1 1048576 | W2 1048576
__global__ __launch_bounds__(256)
void f2b_all(const float* __restrict__ s0, const float* __restrict__ s1,
             const float* __restrict__ s2, const float* __restrict__ s3,
             const float* __restrict__ s4, const float* __restrict__ s5,
             u16* __restrict__ dst) {
  const int i = blockIdx.x * 256 + threadIdx.x;   // < 3145728
  const float* s; int off;
  if (i < 1048576) {
    if (i < 262144)      { s = s0; off = i; }
    else if (i < 524288) { s = s1; off = i - 262144; }
    else if (i < 786432) { s = s2; off = i - 524288; }
    else                 { s = s3; off = i - 786432; }
  } else if (i < 2097152) { s = s4; off = i - 1048576; }
  else                    { s = s5; off = i - 2097152; }
  const float4 v = ((const float4*)s)[off];
  u16x4 o; o[0] = f2bf(v.x); o[1] = f2bf(v.y); o[2] = f2bf(v.z); o[3] = f2bf(v.w);
  ((u16x4*)dst)[i] = o;
}

// ---------------- LayerNorm (1024 cols, 1 block/row) ----------------
__global__ __launch_bounds__(256)
void ln_kernel(const float* __restrict__ x, const float* __restrict__ g,
               const float* __restrict__ b, u16* __restrict__ out) {
  const int row = blockIdx.x, tid = threadIdx.x;
  const float4 v = ((const float4*)(x + (size_t)row * 1024))[tid];
  float s = v.x + v.y + v.z + v.w;
  float s2 = v.x * v.x + v.y * v.y + v.z * v.z + v.w * v.w;
#pragma unroll
  for (int o = 1; o < 64; o <<= 1) { s += __shfl_xor(s, o); s2 += __shfl_xor(s2, o); }
  __shared__ float red[8];
  const int wave = tid >> 6, lane = tid & 63;
  if (lane == 0) { red[wave] = s; red[wave + 4] = s2; }
  __syncthreads();
  s = red[0] + red[1] + red[2] + red[3];
  s2 = red[4] + red[5] + red[6] + red[7];
  const float mu = s * (1.f / 1024.f);
  const float rstd = rsqrtf(s2 * (1.f / 1024.f) - mu * mu + 1e-5f);
  const float4 gg = ((const float4*)g)[tid];
  const float4 bb = ((const float4*)b)[tid];
  u16x4 o4;
  o4[0] = f2bf((v.x - mu) * rstd * gg.x + bb.x);
  o4[1] = f2bf((v.y - mu) * rstd * gg.y + bb.y);
  o4[2] = f2bf((v.z - mu) * rstd * gg.z + bb.z);
  o4[3] = f2bf((v.w - mu) * rstd * gg.w + bb.w);
  ((u16x4*)(out + (size_t)row * 1024))[tid] = o4;
}

// -- fused: out = x + p[0] + p[1] + bo (bf16 partials); hb = LN(out; g,b) --
__global__ __launch_bounds__(256)
void ln_fuse(const float* __restrict__ x, const u16* __restrict__ parts,
             const float* __restrict__ bo, const float* __restrict__ g,
             const float* __restrict__ b, float* __restrict__ out,
             u16* __restrict__ hb) {
  const int row = blockIdx.x, tid = threadIdx.x;
  const size_t base = (size_t)row * 1024;
  const int i4 = row * 256 + tid;
  const float4 xv = ((const float4*)(x + base))[tid];
  const u16x4 h0 = ((const u16x4*)parts)[i4];
  const u16x4 h1 = ((const u16x4*)(parts + 4194304))[i4];
  const float4 bv = ((const float4*)bo)[tid];
  float4 t;
  t.x = xv.x + bf2f(h0[0]) + bf2f(h1[0]) + bv.x;
  t.y = xv.y + bf2f(h0[1]) + bf2f(h1[1]) + bv.y;
  t.z = xv.z + bf2f(h0[2]) + bf2f(h1[2]) + bv.z;
  t.w = xv.w + bf2f(h0[3]) + bf2f(h1[3]) + bv.w;
  ((float4*)(out + base))[tid] = t;
  float s = t.x + t.y + t.z + t.w;
  float s2 = t.x * t.x + t.y * t.y + t.z * t.z + t.w * t.w;
#pragma unroll
  for (int o = 1; o < 64; o <<= 1) { s += __shfl_xor(s, o); s2 += __shfl_xor(s2, o); }
  __shared__ float red[8];
  const int wave = tid >> 6, lane = tid & 63;
  if (lane == 0) { red[wave] = s; red[wave + 4] = s2; }
  __syncthreads();
  s = red[0] + red[1] + red[2] + red[3];
  s2 = red[4] + red[5] + red[6] + red[7];
  const float mu = s * (1.f / 1024.f);
  const float rstd = rsqrtf(s2 * (1.f / 1024.f) - mu * mu + 1e-5f);
  const float4 gg = ((const float4*)g)[tid];
  const float4 bb = ((const float4*)b)[tid];
  u16x4 o4;
  o4[0] = f2bf((t.x - mu) * rstd * gg.x + bb.x);
  o4[1] = f2bf((t.y - mu) * rstd * gg.y + bb.y);
  o4[2] = f2bf((t.z - mu) * rstd * gg.z + bb.z);
  o4[3] = f2bf((t.w - mu) * rstd * gg.w + bb.w);
  ((u16x4*)(hb + base))[tid] = o4;
}

// ------- out += p[0..3] + b2 (MLP2 reduction over 4 bf16 partial slices) -------
__global__ __launch_bounds__(256)
void add4(float* __restrict__ out, const u16* __restrict__ p,
          const float* __restrict__ b2) {
  const int i = blockIdx.x * 256 + threadIdx.x;   // f4 index < 1048576
  const float4 o = ((const float4*)out)[i];
  const float4 bv = ((const float4*)b2)[i & 255];
  float a0 = o.x + bv.x, a1 = o.y + bv.y, a2 = o.z + bv.z, a3 = o.w + bv.w;
#pragma unroll
  for (int kz = 0; kz < 4; kz++) {
    const u16x4 h = ((const u16x4*)(p + (size_t)kz * 4194304))[i];
    a0 += bf2f(h[0]); a1 += bf2f(h[1]); a2 += bf2f(h[2]); a3 += bf2f(h[3]);
  }
  float4 r; r.x = a0; r.y = a1; r.z = a2; r.w = a3;
  ((float4*)out)[i] = r;
}

// ---------------- GEMM C = A * B^T, A[M,ldk] bf16, B[N,ldk] bf16 ----------------
// BM=128, BN=128. 4 waves 2x2; m97 structure. blockIdx.z = split-K slice (len K).
template <class Epi>
__global__ __launch_bounds__(256)
void gemm_bt(const u16* __restrict__ A, const u16* __restrict__ Bw,
             int ldk, int K, Epi epi) {
  __shared__ __align__(16) u16 As[128 * 32];
  __shared__ __align__(16) u16 Bs[128 * 32];
  const int tid = threadIdx.x;
  const int wave = tid >> 6, lane = tid & 63;
  const int quad = lane >> 4, l16 = lane & 15;
  const int bm = blockIdx.x * 128, bn = blockIdx.y * 128;
  const int kz = blockIdx.z;
  const int wm = (wave & 1) * 64, wn = (wave >> 1) * 64;

  const int srow = lane >> 2, scol = (lane & 3) * 8;
  const u16* pa0 = A + (size_t)(bm + wave * 32 + srow) * ldk + (size_t)kz * K + scol;
  const u16* pa1 = pa0 + (size_t)16 * ldk;
  const u16* pb0 = Bw + (size_t)(bn + wave * 32 + srow) * ldk + (size_t)kz * K + scol;
  const u16* pb1 = pb0 + (size_t)16 * ldk;
  u16* la0 = &As[wave * 1024];
  u16* la1 = la0 + 512;
  u16* lb0 = &Bs[wave * 1024];
  u16* lb1 = lb0 + 512;

  const f32x4 fz = {0.f, 0.f, 0.f, 0.f};
  f32x4 acc[4][4];
#pragma unroll
  for (int i = 0; i < 4; i++)
#pragma unroll
    for (int j = 0; j < 4; j++) acc[i][j] = fz;

  for (int k0 = 0; k0 < K; k0 += 32) {
    async_load16(pa0, la0);
    async_load16(pa1, la1);
    async_load16(pb0, lb0);
    async_load16(pb1, lb1);
    pa0 += 32; pa1 += 32; pb0 += 32; pb1 += 32;
    __syncthreads();
    bf16x8 af[4], bfr[4];
#pragma unroll
    for (int mi = 0; mi < 4; mi++)
      af[mi] = *(const bf16x8*)&As[(wm + mi * 16 + l16) * 32 + quad * 8];
#pragma unroll
    for (int ni = 0; ni < 4; ni++)
      bfr[ni] = *(const bf16x8*)&Bs[(wn + ni * 16 + l16) * 32 + quad * 8];
#pragma unroll
    for (int mi = 0; mi < 4; mi++)
#pragma unroll
      for (int ni = 0; ni < 4; ni++)
        acc[mi][ni] = __builtin_amdgcn_mfma_f32_16x16x32_bf16(af[mi], bfr[ni], acc[mi][ni], 0, 0, 0);
    __syncthreads();
  }
#pragma unroll
  for (int mi = 0; mi < 4; mi++)
#pragma unroll
    for (int ni = 0; ni < 4; ni++)
      epi(bm + wm + mi * 16 + quad * 4, bn + wn + ni * 16 + l16, kz, acc[mi][ni]);
}

// ---------------- epilogues (rows m0..m0+3, col n) ----------------
struct EpiQKV {   // q[b,h,s,e] scaled by 0.125*log2(e); k[b,h,s,e]; v^T[b,h,e,s]
  u16 *q, *k, *vt; const float *bq, *bk, *bv;
  __device__ void operator()(int m0, int n, int, f32x4 v) const {
    const int which = n >> 10, nn = n & 1023;
    const int hh = nn >> 6, e = nn & 63;
    const int bb = m0 >> 11, s0 = m0 & 2047;
    const size_t bh = (size_t)(bb * 16 + hh);
    if (which == 0) {
      const float bias = bq[nn];
      u16* p = &q[(bh * 2048 + s0) * 64 + e];
#pragma unroll
      for (int r = 0; r < 4; r++) p[r * 64] = bf_bits((v[r] + bias) * 0.18033688f);
    } else if (which == 1) {
      const float bias = bk[nn];
      u16* p = &k[(bh * 2048 + s0) * 64 + e];
#pragma unroll
      for (int r = 0; r < 4; r++) p[r * 64] = bf_bits(v[r] + bias);
    } else {
      const float bias = bv[nn];
      bf16x4 pk;
#pragma unroll
      for (int r = 0; r < 4; r++) pk[r] = (__bf16)(v[r] + bias);
      *(bf16x4*)&vt[(bh * 64 + e) * 2048 + s0] = pk;
    }
  }
};
struct EpiPartB {  // bf16 split-K partial -> p + kz*4194304  ([4096,1024] bf16)
  u16* p;
  __device__ void operator()(int m0, int n, int kz, f32x4 v) const {
    u16* pp = p + (size_t)kz * 4194304;
#pragma unroll
    for (int r = 0; r < 4; r++) pp[(size_t)(m0 + r) * 1024 + n] = bf_bits(v[r]);
  }
};
struct EpiGelu {  // gelu(u) = u * sigmoid(2*c*(u+0.044715u^3)) via exp2
  const float* b1; u16* o;
  __device__ void operator()(int m0, int n, int, f32x4 v) const {
    const float bias = b1[n];
#pragma unroll
    for (int r = 0; r < 4; r++) {
      const float u = v[r] + bias;
      const float z2 = u * (2.3021183f + 0.10294515f * u * u);
      const float d = 1.0f + exp2_fast(-z2);
      o[(size_t)(m0 + r) * 4096 + n] = bf_bits(u * rcp_fast(d));
    }
  }
};

// ---------------- flash attention, no-max softmax, 1 wave = 32 q-rows ----------------
__global__ __launch_bounds__(256)
void attn_kernel(const u16* __restrict__ Q, const u16* __restrict__ K,
                 const u16* __restrict__ Vt, u16* __restrict__ O) {
  __shared__ __align__(16) u16 Ks[64 * 72];
  __shared__ __align__(16) u16 Vs[64 * 72];
  __shared__ __align__(16) u16 Ps[4][32 * 72];
  const int tid = threadIdx.x, wave = tid >> 6, lane = tid & 63;
  const int quad = lane >> 4, l16 = lane & 15;
  const int b = blockIdx.z, h = blockIdx.y, qt = blockIdx.x;
  const size_t bh = (size_t)(b * 16 + h);
  const u16* Qp = Q + bh * (size_t)(2048 * 64);
  const u16* Kp = K + bh * (size_t)(2048 * 64);
  const u16* Vp = Vt + bh * (size_t)(64 * 2048);
  const int q0 = qt * 128 + wave * 32;

  bf16x8 qf[2][2];
#pragma unroll
  for (int rg = 0; rg < 2; rg++) {
    const u16* qrow = &Qp[(size_t)(q0 + rg * 16 + l16) * 64 + quad * 8];
    qf[rg][0] = *(const bf16x8*)qrow;
    qf[rg][1] = *(const bf16x8*)(qrow + 32);
  }

  const int sr = tid >> 2, sc = (tid & 3) * 16;
  const int krow = 4 * (sr & 15) + (sr >> 4);          // permuted key row
  const u16* kg = &Kp[(size_t)krow * 64 + sc];
  const u16* vg = &Vp[(size_t)sr * 2048 + sc];
  u16* kl = &Ks[sr * 72 + sc];
  u16* vl = &Vs[sr * 72 + sc];
  u16* Pw = &Ps[wave][0];

  bf16x8 ones;
#pragma unroll
  for (int i = 0; i < 8; i++) ones[i] = (__bf16)1.0f;

  const f32x4 fz = {0.f, 0.f, 0.f, 0.f};
  f32x4 acc[2][4], lsum[2];
#pragma unroll
  for (int rg = 0; rg < 2; rg++) {
    lsum[rg] = fz;
#pragma unroll
    for (int g = 0; g < 4; g++) acc[rg][g] = fz;
  }

  bf16x8 pk0 = *(const bf16x8*)kg, pk1 = *(const bf16x8*)(kg + 8);
  bf16x8 pv0 = *(const bf16x8*)vg, pv1 = *(const bf16x8*)(vg + 8);

  for (int t0 = 0; t0 < 2048; t0 += 64) {
    *(bf16x8*)kl = pk0; *(bf16x8*)(kl + 8) = pk1;
    *(bf16x8*)vl = pv0; *(bf16x8*)(vl + 8) = pv1;
    __syncthreads();
    kg += 64 * 64; vg += 64;
    pk0 = *(const bf16x8*)kg; pk1 = *(const bf16x8*)(kg + 8);
    pv0 = *(const bf16x8*)vg; pv1 = *(const bf16x8*)(vg + 8);

    f32x4 s[2][4];
#pragma unroll
    for (int g = 0; g < 4; g++) {
      const u16* kr = &Ks[(g * 16 + l16) * 72 + quad * 8];
      const bf16x8 kb0 = *(const bf16x8*)kr;
      const bf16x8 kb1 = *(const bf16x8*)(kr + 32);
#pragma unroll
      for (int rg = 0; rg < 2; rg++) {
        f32x4 z = __builtin_amdgcn_mfma_f32_16x16x32_bf16(qf[rg][0], kb0, fz, 0, 0, 0);
        s[rg][g] = __builtin_amdgcn_mfma_f32_16x16x32_bf16(qf[rg][1], kb1, z, 0, 0, 0);
      }
    }
#pragma unroll
    for (int rg = 0; rg < 2; rg++)
#pragma unroll
      for (int r = 0; r < 4; r++) {
        f32x4 pf;
#pragma unroll
        for (int g = 0; g < 4; g++) pf[g] = exp2_fast(s[rg][g][r]);
        const bf16x4 pb = __builtin_convertvector(pf, bf16x4);
        *(bf16x4*)&Pw[(rg * 16 + quad * 4 + r) * 72 + 4 * l16] = pb;
      }
    bf16x8 pa[2][2];
#pragma unroll
    for (int rg = 0; rg < 2; rg++) {
      const u16* pr = &Pw[(rg * 16 + l16) * 72 + quad * 8];
      pa[rg][0] = *(const bf16x8*)pr;
      pa[rg][1] = *(const bf16x8*)(pr + 32);
      lsum[rg] = __builtin_amdgcn_mfma_f32_16x16x32_bf16(pa[rg][0], ones, lsum[rg], 0, 0, 0);
      lsum[rg] = __builtin_amdgcn_mfma_f32_16x16x32_bf16(pa[rg][1], ones, lsum[rg], 0, 0, 0);
    }
#pragma unroll
    for (int g = 0; g < 4; g++) {
      const u16* vr = &Vs[(g * 16 + l16) * 72 + quad * 8];
      const bf16x8 vb0 = *(const bf16x8*)vr;
      const bf16x8 vb1 = *(const bf16x8*)(vr + 32);
#pragma unroll
      for (int rg = 0; rg < 2; rg++) {
        acc[rg][g] = __builtin_amdgcn_mfma_f32_16x16x32_bf16(pa[rg][0], vb0, acc[rg][g], 0, 0, 0);
        acc[rg][g] = __builtin_amdgcn_mfma_f32_16x16x32_bf16(pa[rg][1], vb1, acc[rg][g], 0, 0, 0);
      }
    }
    __syncthreads();
  }
#pragma unroll
  for (int rg = 0; rg < 2; rg++)
#pragma unroll
    for (int r = 0; r < 4; r++) {
      const float inv = rcp_fast(lsum[rg][r]);
      const int s_row = q0 + rg * 16 + quad * 4 + r;
      u16* op = (u16*)&O[((size_t)(b * 2048 + s_row)) * 1024 + h * 64 + l16];
#pragma unroll
      for (int g = 0; g < 4; g++) op[g * 16] = bf_bits(acc[rg][g][r] * inv);
    }
}

// ---------------- launch ----------------
extern "C" void kernel_launch(void* const* d_in, const int* in_sizes, int n_in,
                              void* d_out, int out_size, void* d_ws, size_t ws_size,
                              hipStream_t stream) {
  const float* x   = (const float*)d_in[0];
  const float* Wq  = (const float*)d_in[1];
  const float* bq  = (const float*)d_in[2];
  const float* Wk  = (const float*)d_in[3];
  const float* bk  = (const float*)d_in[4];
  const float* Wv  = (const float*)d_in[5];
  const float* bv  = (const float*)d_in[6];
  const float* Wo  = (const float*)d_in[7];
  const float* bo  = (const float*)d_in[8];
  const float* g1  = (const float*)d_in[9];
  const float* be1 = (const float*)d_in[10];
  const float* W1  = (const float*)d_in[11];
  const float* b1  = (const float*)d_in[12];
  const float* W2  = (const float*)d_in[13];
  const float* b2  = (const float*)d_in[14];
  const float* g2  = (const float*)d_in[15];
  const float* be2 = (const float*)d_in[16];
  float* out = (float*)d_out;

  char* w = (char*)d_ws;
  u16* wqkv = (u16*)w; w += (size_t)3072 * 1024 * 2;   // contiguous bf16 weights:
  u16* wob  = (u16*)w; w += (size_t)1024 * 1024 * 2;   //   wqkv|wob|w1b|w2b
  u16* w1b  = (u16*)w; w += (size_t)4096 * 1024 * 2;
  u16* w2b  = (u16*)w; w += (size_t)1024 * 4096 * 2;
  u16* hb   = (u16*)w; w += (size_t)4096 * 1024 * 2;
  u16* qb   = (u16*)w; w += (size_t)4096 * 1024 * 2;   // later: MLP2 partials (4x8MB
  u16* kb   = (u16*)w; w += (size_t)4096 * 1024 * 2;   //   bf16 spanning qb..atb)
  u16* vtb  = (u16*)w; w += (size_t)4096 * 1024 * 2;
  u16* atb  = (u16*)w; w += (size_t)4096 * 1024 * 2;
  u16* m1b  = (u16*)w; w += (size_t)4096 * 4096 * 2;   // O-proj partials first (2x8MB)

  u16* op_part = m1b;   // O-proj bf16 partials, dead before MLP1 writes m1b
  u16* ml_part = qb;    // MLP2 bf16 partials, qb..atb all dead after O-proj

  f2b_all<<<12288, 256, 0, stream>>>(Wq, Wk, Wv, Wo, W1, W2, wqkv);

  ln_kernel<<<4096, 256, 0, stream>>>(x, g1, be1, hb);
  gemm_bt<EpiQKV><<<dim3(32, 24, 1), 256, 0, stream>>>(hb, wqkv, 1024, 1024,
      EpiQKV{qb, kb, vtb, bq, bk, bv});
  attn_kernel<<<dim3(16, 16, 2), 256, 0, stream>>>(qb, kb, vtb, atb);
  gemm_bt<EpiPartB><<<dim3(32, 8, 2), 256, 0, stream>>>(atb, wob, 1024, 512,
      EpiPartB{op_part});
  ln_fuse<<<4096, 256, 0, stream>>>(x, op_part, bo, g2, be2, out, hb);
  gemm_bt<EpiGelu><<<dim3(32, 32, 1), 256, 0, stream>>>(hb, w1b, 1024, 1024,
      EpiGelu{b1, m1b});
  gemm_bt<EpiPartB><<<dim3(32, 8, 4), 256, 0, stream>>>(m1b, w2b, 4096, 1024,
      EpiPartB{ml_part});
  add4<<<4096, 256, 0, stream>>>(out, ml_part, b2);
}

// Round 6
// 359.431 us; speedup vs baseline: 1.4821x; 1.0728x over previous
//
#include <hip/hip_runtime.h>

typedef unsigned short u16;
typedef __attribute__((ext_vector_type(8))) __bf16 bf16x8;
typedef __attribute__((ext_vector_type(4))) __bf16 bf16x4;
typedef __attribute__((ext_vector_type(4))) float f32x4;
typedef __attribute__((ext_vector_type(4))) unsigned short u16x4;

#define AS1 __attribute__((address_space(1)))
#define AS3 __attribute__((address_space(3)))

__device__ __forceinline__ void async_load16(const void* g, void* l) {
  __builtin_amdgcn_global_load_lds((const AS1 void*)g, (AS3 void*)l, 16, 0, 0);
}

__device__ __forceinline__ float exp2_fast(float x) {
#if __has_builtin(__builtin_amdgcn_exp2f)
  return __builtin_amdgcn_exp2f(x);
#else
  return exp2f(x);
#endif
}
__device__ __forceinline__ float rcp_fast(float x) {
#if __has_builtin(__builtin_amdgcn_rcpf)
  return __builtin_amdgcn_rcpf(x);
#else
  return 1.0f / x;
#endif
}

__device__ __forceinline__ u16 f2bf(float f) {   // manual RNE
  union { float f; unsigned u; } a; a.f = f;
  unsigned u = a.u;
  u += 0x7fffu + ((u >> 16) & 1u);
  return (u16)(u >> 16);
}
__device__ __forceinline__ u16 bf_bits(float f) {  // native cvt (RNE)
  union { __bf16 b; u16 u; } c; c.b = (__bf16)f; return c.u;
}
__device__ __forceinline__ float bf2f(u16 h) {
  union { unsigned u; float f; } c; c.u = ((unsigned)h) << 16; return c.f;
}

// ------- fp32 -> bf16: all 6 weights in ONE launch (dst contiguous in ws) -------
__global__ __launch_bounds__(256)
void f2b_all(const float* __restrict__ s0, const float* __restrict__ s1,
             const float* __restrict__ s2, const float* __restrict__ s3,
             const float* __restrict__ s4, const float* __restrict__ s5,
             u16* __restrict__ dst) {
  const int i = blockIdx.x * 256 + threadIdx.x;   // < 3145728
  const float* s; int off;
  if (i < 1048576) {
    if (i < 262144)      { s = s0; off = i; }
    else if (i < 524288) { s = s1; off = i - 262144; }
    else if (i < 786432) { s = s2; off = i - 524288; }
    else                 { s = s3; off = i - 786432; }
  } else if (i < 2097152) { s = s4; off = i - 1048576; }
  else                    { s = s5; off = i - 2097152; }
  const float4 v = ((const float4*)s)[off];
  u16x4 o; o[0] = f2bf(v.x); o[1] = f2bf(v.y); o[2] = f2bf(v.z); o[3] = f2bf(v.w);
  ((u16x4*)dst)[i] = o;
}

// ---------------- LayerNorm (1024 cols, 1 block/row) ----------------
__global__ __launch_bounds__(256)
void ln_kernel(const float* __restrict__ x, const float* __restrict__ g,
               const float* __restrict__ b, u16* __restrict__ out) {
  const int row = blockIdx.x, tid = threadIdx.x;
  const float4 v = ((const float4*)(x + (size_t)row * 1024))[tid];
  float s = v.x + v.y + v.z + v.w;
  float s2 = v.x * v.x + v.y * v.y + v.z * v.z + v.w * v.w;
#pragma unroll
  for (int o = 1; o < 64; o <<= 1) { s += __shfl_xor(s, o); s2 += __shfl_xor(s2, o); }
  __shared__ float red[8];
  const int wave = tid >> 6, lane = tid & 63;
  if (lane == 0) { red[wave] = s; red[wave + 4] = s2; }
  __syncthreads();
  s = red[0] + red[1] + red[2] + red[3];
  s2 = red[4] + red[5] + red[6] + red[7];
  const float mu = s * (1.f / 1024.f);
  const float rstd = rsqrtf(s2 * (1.f / 1024.f) - mu * mu + 1e-5f);
  const float4 gg = ((const float4*)g)[tid];
  const float4 bb = ((const float4*)b)[tid];
  u16x4 o4;
  o4[0] = f2bf((v.x - mu) * rstd * gg.x + bb.x);
  o4[1] = f2bf((v.y - mu) * rstd * gg.y + bb.y);
  o4[2] = f2bf((v.z - mu) * rstd * gg.z + bb.z);
  o4[3] = f2bf((v.w - mu) * rstd * gg.w + bb.w);
  ((u16x4*)(out + (size_t)row * 1024))[tid] = o4;
}

// -- fused: out = x + p[0] + p[1] + bo (bf16 partials); hb = LN(out; g,b) --
__global__ __launch_bounds__(256)
void ln_fuse(const float* __restrict__ x, const u16* __restrict__ parts,
             const float* __restrict__ bo, const float* __restrict__ g,
             const float* __restrict__ b, float* __restrict__ out,
             u16* __restrict__ hb) {
  const int row = blockIdx.x, tid = threadIdx.x;
  const size_t base = (size_t)row * 1024;
  const int i4 = row * 256 + tid;
  const float4 xv = ((const float4*)(x + base))[tid];
  const u16x4 h0 = ((const u16x4*)parts)[i4];
  const u16x4 h1 = ((const u16x4*)(parts + 4194304))[i4];
  const float4 bv = ((const float4*)bo)[tid];
  float4 t;
  t.x = xv.x + bf2f(h0[0]) + bf2f(h1[0]) + bv.x;
  t.y = xv.y + bf2f(h0[1]) + bf2f(h1[1]) + bv.y;
  t.z = xv.z + bf2f(h0[2]) + bf2f(h1[2]) + bv.z;
  t.w = xv.w + bf2f(h0[3]) + bf2f(h1[3]) + bv.w;
  ((float4*)(out + base))[tid] = t;
  float s = t.x + t.y + t.z + t.w;
  float s2 = t.x * t.x + t.y * t.y + t.z * t.z + t.w * t.w;
#pragma unroll
  for (int o = 1; o < 64; o <<= 1) { s += __shfl_xor(s, o); s2 += __shfl_xor(s2, o); }
  __shared__ float red[8];
  const int wave = tid >> 6, lane = tid & 63;
  if (lane == 0) { red[wave] = s; red[wave + 4] = s2; }
  __syncthreads();
  s = red[0] + red[1] + red[2] + red[3];
  s2 = red[4] + red[5] + red[6] + red[7];
  const float mu = s * (1.f / 1024.f);
  const float rstd = rsqrtf(s2 * (1.f / 1024.f) - mu * mu + 1e-5f);
  const float4 gg = ((const float4*)g)[tid];
  const float4 bb = ((const float4*)b)[tid];
  u16x4 o4;
  o4[0] = f2bf((t.x - mu) * rstd * gg.x + bb.x);
  o4[1] = f2bf((t.y - mu) * rstd * gg.y + bb.y);
  o4[2] = f2bf((t.z - mu) * rstd * gg.z + bb.z);
  o4[3] = f2bf((t.w - mu) * rstd * gg.w + bb.w);
  ((u16x4*)(hb + base))[tid] = o4;
}

// ------- out += p[0..3] + b2 (MLP2 reduction over 4 bf16 partial slices) -------
__global__ __launch_bounds__(256)
void add4(float* __restrict__ out, const u16* __restrict__ p,
          const float* __restrict__ b2) {
  const int i = blockIdx.x * 256 + threadIdx.x;   // f4 index < 1048576
  const float4 o = ((const float4*)out)[i];
  const float4 bv = ((const float4*)b2)[i & 255];
  float a0 = o.x + bv.x, a1 = o.y + bv.y, a2 = o.z + bv.z, a3 = o.w + bv.w;
#pragma unroll
  for (int kz = 0; kz < 4; kz++) {
    const u16x4 h = ((const u16x4*)(p + (size_t)kz * 4194304))[i];
    a0 += bf2f(h[0]); a1 += bf2f(h[1]); a2 += bf2f(h[2]); a3 += bf2f(h[3]);
  }
  float4 r; r.x = a0; r.y = a1; r.z = a2; r.w = a3;
  ((float4*)out)[i] = r;
}

// ---------------- GEMM C = A * B^T, A[M,ldk] bf16, B[N,ldk] bf16 ----------------
// BM=256, BN=128, BK=32; 4 waves, wave tile 64x128 (acc 4x8). M fixed = 4096
// (16 m-blocks). 1-D grid, id = m + 16*(n + NB*kz): same-m blocks land on the
// same XCD (id%8 round-robin heuristic) so the 256xK A-slab stays in that
// XCD's L2 while B streams. Epi gets (row0, col, kz, f32x4 of 4 rows).
template <class Epi>
__global__ __launch_bounds__(256, 2)
void gemm_bt(const u16* __restrict__ A, const u16* __restrict__ Bw,
             int ldk, int K, int NB, Epi epi) {
  __shared__ __align__(16) u16 As[256 * 32];   // 16 KB
  __shared__ __align__(16) u16 Bs[128 * 32];   // 8 KB
  const int tid = threadIdx.x;
  const int wave = tid >> 6, lane = tid & 63;
  const int quad = lane >> 4, l16 = lane & 15;
  const int id = blockIdx.x;
  const int mb = id & 15;
  const int t = id >> 4;
  const int nb = t % NB;
  const int kz = t / NB;
  const int bm = mb * 256, bn = nb * 128;
  const int wm = wave * 64;

  const int srow = lane >> 2, scol = (lane & 3) * 8;
  // A: 4 staging instrs/thread (rows wave*64 + j*16 + srow)
  const u16* pa[4];
  u16* la[4];
#pragma unroll
  for (int j = 0; j < 4; j++) {
    pa[j] = A + (size_t)(bm + wave * 64 + j * 16 + srow) * ldk + (size_t)kz * K + scol;
    la[j] = &As[wave * 2048 + j * 512];
  }
  // B: 2 staging instrs/thread (rows wave*32 + j*16 + srow)
  const u16* pb[2];
  u16* lb[2];
#pragma unroll
  for (int j = 0; j < 2; j++) {
    pb[j] = Bw + (size_t)(bn + wave * 32 + j * 16 + srow) * ldk + (size_t)kz * K + scol;
    lb[j] = &Bs[wave * 1024 + j * 512];
  }

  const f32x4 fz = {0.f, 0.f, 0.f, 0.f};
  f32x4 acc[4][8];
#pragma unroll
  for (int i = 0; i < 4; i++)
#pragma unroll
    for (int j = 0; j < 8; j++) acc[i][j] = fz;

  for (int k0 = 0; k0 < K; k0 += 32) {
#pragma unroll
    for (int j = 0; j < 4; j++) { async_load16(pa[j], la[j]); pa[j] += 32; }
#pragma unroll
    for (int j = 0; j < 2; j++) { async_load16(pb[j], lb[j]); pb[j] += 32; }
    __syncthreads();
    bf16x8 af[4], bfr[8];
#pragma unroll
    for (int mi = 0; mi < 4; mi++)
      af[mi] = *(const bf16x8*)&As[(wm + mi * 16 + l16) * 32 + quad * 8];
#pragma unroll
    for (int ni = 0; ni < 8; ni++)
      bfr[ni] = *(const bf16x8*)&Bs[(ni * 16 + l16) * 32 + quad * 8];
#pragma unroll
    for (int mi = 0; mi < 4; mi++)
#pragma unroll
      for (int ni = 0; ni < 8; ni++)
        acc[mi][ni] = __builtin_amdgcn_mfma_f32_16x16x32_bf16(af[mi], bfr[ni], acc[mi][ni], 0, 0, 0);
    __syncthreads();
  }
#pragma unroll
  for (int mi = 0; mi < 4; mi++)
#pragma unroll
    for (int ni = 0; ni < 8; ni++)
      epi(bm + wm + mi * 16 + quad * 4, bn + ni * 16 + l16, kz, acc[mi][ni]);
}

// ---------------- epilogues (rows m0..m0+3, col n) ----------------
struct EpiQKV {   // q[b,h,s,e] scaled by 0.125*log2(e); k[b,h,s,e]; v^T[b,h,e,s]
  u16 *q, *k, *vt; const float *bq, *bk, *bv;
  __device__ void operator()(int m0, int n, int, f32x4 v) const {
    const int which = n >> 10, nn = n & 1023;
    const int hh = nn >> 6, e = nn & 63;
    const int bb = m0 >> 11, s0 = m0 & 2047;
    const size_t bh = (size_t)(bb * 16 + hh);
    if (which == 0) {
      const float bias = bq[nn];
      u16* p = &q[(bh * 2048 + s0) * 64 + e];
#pragma unroll
      for (int r = 0; r < 4; r++) p[r * 64] = bf_bits((v[r] + bias) * 0.18033688f);
    } else if (which == 1) {
      const float bias = bk[nn];
      u16* p = &k[(bh * 2048 + s0) * 64 + e];
#pragma unroll
      for (int r = 0; r < 4; r++) p[r * 64] = bf_bits(v[r] + bias);
    } else {
      const float bias = bv[nn];
      bf16x4 pk;
#pragma unroll
      for (int r = 0; r < 4; r++) pk[r] = (__bf16)(v[r] + bias);
      *(bf16x4*)&vt[(bh * 64 + e) * 2048 + s0] = pk;
    }
  }
};
struct EpiPartB {  // bf16 split-K partial -> p + kz*4194304  ([4096,1024] bf16)
  u16* p;
  __device__ void operator()(int m0, int n, int kz, f32x4 v) const {
    u16* pp = p + (size_t)kz * 4194304;
#pragma unroll
    for (int r = 0; r < 4; r++) pp[(size_t)(m0 + r) * 1024 + n] = bf_bits(v[r]);
  }
};
struct EpiGelu {  // gelu(u) = u * sigmoid(2*c*(u+0.044715u^3)) via exp2
  const float* b1; u16* o;
  __device__ void operator()(int m0, int n, int, f32x4 v) const {
    const float bias = b1[n];
#pragma unroll
    for (int r = 0; r < 4; r++) {
      const float u = v[r] + bias;
      const float z2 = u * (2.3021183f + 0.10294515f * u * u);
      const float d = 1.0f + exp2_fast(-z2);
      o[(size_t)(m0 + r) * 4096 + n] = bf_bits(u * rcp_fast(d));
    }
  }
};

// ---------------- flash attention, no-max softmax, 1 wave = 32 q-rows ----------------
__global__ __launch_bounds__(256)
void attn_kernel(const u16* __restrict__ Q, const u16* __restrict__ K,
                 const u16* __restrict__ Vt, u16* __restrict__ O) {
  __shared__ __align__(16) u16 Ks[64 * 72];
  __shared__ __align__(16) u16 Vs[64 * 72];
  __shared__ __align__(16) u16 Ps[4][32 * 72];
  const int tid = threadIdx.x, wave = tid >> 6, lane = tid & 63;
  const int quad = lane >> 4, l16 = lane & 15;
  const int b = blockIdx.z, h = blockIdx.y, qt = blockIdx.x;
  const size_t bh = (size_t)(b * 16 + h);
  const u16* Qp = Q + bh * (size_t)(2048 * 64);
  const u16* Kp = K + bh * (size_t)(2048 * 64);
  const u16* Vp = Vt + bh * (size_t)(64 * 2048);
  const int q0 = qt * 128 + wave * 32;

  bf16x8 qf[2][2];
#pragma unroll
  for (int rg = 0; rg < 2; rg++) {
    const u16* qrow = &Qp[(size_t)(q0 + rg * 16 + l16) * 64 + quad * 8];
    qf[rg][0] = *(const bf16x8*)qrow;
    qf[rg][1] = *(const bf16x8*)(qrow + 32);
  }

  const int sr = tid >> 2, sc = (tid & 3) * 16;
  const int krow = 4 * (sr & 15) + (sr >> 4);          // permuted key row
  const u16* kg = &Kp[(size_t)krow * 64 + sc];
  const u16* vg = &Vp[(size_t)sr * 2048 + sc];
  u16* kl = &Ks[sr * 72 + sc];
  u16* vl = &Vs[sr * 72 + sc];
  u16* Pw = &Ps[wave][0];

  bf16x8 ones;
#pragma unroll
  for (int i = 0; i < 8; i++) ones[i] = (__bf16)1.0f;

  const f32x4 fz = {0.f, 0.f, 0.f, 0.f};
  f32x4 acc[2][4], lsum[2];
#pragma unroll
  for (int rg = 0; rg < 2; rg++) {
    lsum[rg] = fz;
#pragma unroll
    for (int g = 0; g < 4; g++) acc[rg][g] = fz;
  }

  bf16x8 pk0 = *(const bf16x8*)kg, pk1 = *(const bf16x8*)(kg + 8);
  bf16x8 pv0 = *(const bf16x8*)vg, pv1 = *(const bf16x8*)(vg + 8);

  for (int t0 = 0; t0 < 2048; t0 += 64) {
    *(bf16x8*)kl = pk0; *(bf16x8*)(kl + 8) = pk1;
    *(bf16x8*)vl = pv0; *(bf16x8*)(vl + 8) = pv1;
    __syncthreads();
    kg += 64 * 64; vg += 64;
    pk0 = *(const bf16x8*)kg; pk1 = *(const bf16x8*)(kg + 8);
    pv0 = *(const bf16x8*)vg; pv1 = *(const bf16x8*)(vg + 8);

    f32x4 s[2][4];
#pragma unroll
    for (int g = 0; g < 4; g++) {
      const u16* kr = &Ks[(g * 16 + l16) * 72 + quad * 8];
      const bf16x8 kb0 = *(const bf16x8*)kr;
      const bf16x8 kb1 = *(const bf16x8*)(kr + 32);
#pragma unroll
      for (int rg = 0; rg < 2; rg++) {
        f32x4 z = __builtin_amdgcn_mfma_f32_16x16x32_bf16(qf[rg][0], kb0, fz, 0, 0, 0);
        s[rg][g] = __builtin_amdgcn_mfma_f32_16x16x32_bf16(qf[rg][1], kb1, z, 0, 0, 0);
      }
    }
#pragma unroll
    for (int rg = 0; rg < 2; rg++)
#pragma unroll
      for (int r = 0; r < 4; r++) {
        f32x4 pf;
#pragma unroll
        for (int g = 0; g < 4; g++) pf[g] = exp2_fast(s[rg][g][r]);
        const bf16x4 pb = __builtin_convertvector(pf, bf16x4);
        *(bf16x4*)&Pw[(rg * 16 + quad * 4 + r) * 72 + 4 * l16] = pb;
      }
    bf16x8 pa[2][2];
#pragma unroll
    for (int rg = 0; rg < 2; rg++) {
      const u16* pr = &Pw[(rg * 16 + l16) * 72 + quad * 8];
      pa[rg][0] = *(const bf16x8*)pr;
      pa[rg][1] = *(const bf16x8*)(pr + 32);
      lsum[rg] = __builtin_amdgcn_mfma_f32_16x16x32_bf16(pa[rg][0], ones, lsum[rg], 0, 0, 0);
      lsum[rg] = __builtin_amdgcn_mfma_f32_16x16x32_bf16(pa[rg][1], ones, lsum[rg], 0, 0, 0);
    }
#pragma unroll
    for (int g = 0; g < 4; g++) {
      const u16* vr = &Vs[(g * 16 + l16) * 72 + quad * 8];
      const bf16x8 vb0 = *(const bf16x8*)vr;
      const bf16x8 vb1 = *(const bf16x8*)(vr + 32);
#pragma unroll
      for (int rg = 0; rg < 2; rg++) {
        acc[rg][g] = __builtin_amdgcn_mfma_f32_16x16x32_bf16(pa[rg][0], vb0, acc[rg][g], 0, 0, 0);
        acc[rg][g] = __builtin_amdgcn_mfma_f32_16x16x32_bf16(pa[rg][1], vb1, acc[rg][g], 0, 0, 0);
      }
    }
    __syncthreads();
  }
#pragma unroll
  for (int rg = 0; rg < 2; rg++)
#pragma unroll
    for (int r = 0; r < 4; r++) {
      const float inv = rcp_fast(lsum[rg][r]);
      const int s_row = q0 + rg * 16 + quad * 4 + r;
      u16* op = (u16*)&O[((size_t)(b * 2048 + s_row)) * 1024 + h * 64 + l16];
#pragma unroll
      for (int g = 0; g < 4; g++) op[g * 16] = bf_bits(acc[rg][g][r] * inv);
    }
}

// ---------------- launch ----------------
extern "C" void kernel_launch(void* const* d_in, const int* in_sizes, int n_in,
                              void* d_out, int out_size, void* d_ws, size_t ws_size,
                              hipStream_t stream) {
  const float* x   = (const float*)d_in[0];
  const float* Wq  = (const float*)d_in[1];
  const float* bq  = (const float*)d_in[2];
  const float* Wk  = (const float*)d_in[3];
  const float* bk  = (const float*)d_in[4];
  const float* Wv  = (const float*)d_in[5];
  const float* bv  = (const float*)d_in[6];
  const float* Wo  = (const float*)d_in[7];
  const float* bo  = (const float*)d_in[8];
  const float* g1  = (const float*)d_in[9];
  const float* be1 = (const float*)d_in[10];
  const float* W1  = (const float*)d_in[11];
  const float* b1  = (const float*)d_in[12];
  const float* W2  = (const float*)d_in[13];
  const float* b2  = (const float*)d_in[14];
  const float* g2  = (const float*)d_in[15];
  const float* be2 = (const float*)d_in[16];
  float* out = (float*)d_out;

  char* w = (char*)d_ws;
  u16* wqkv = (u16*)w; w += (size_t)3072 * 1024 * 2;   // contiguous bf16 weights:
  u16* wob  = (u16*)w; w += (size_t)1024 * 1024 * 2;   //   wqkv|wob|w1b|w2b
  u16* w1b  = (u16*)w; w += (size_t)4096 * 1024 * 2;
  u16* w2b  = (u16*)w; w += (size_t)1024 * 4096 * 2;
  u16* hb   = (u16*)w; w += (size_t)4096 * 1024 * 2;
  u16* qb   = (u16*)w; w += (size_t)4096 * 1024 * 2;   // later: MLP2 partials (4x8MB
  u16* kb   = (u16*)w; w += (size_t)4096 * 1024 * 2;   //   bf16 spanning qb..atb)
  u16* vtb  = (u16*)w; w += (size_t)4096 * 1024 * 2;
  u16* atb  = (u16*)w; w += (size_t)4096 * 1024 * 2;
  u16* m1b  = (u16*)w; w += (size_t)4096 * 4096 * 2;   // O-proj partials first (2x8MB)

  u16* op_part = m1b;   // O-proj bf16 partials, dead before MLP1 writes m1b
  u16* ml_part = qb;    // MLP2 bf16 partials, qb..atb all dead after O-proj

  f2b_all<<<12288, 256, 0, stream>>>(Wq, Wk, Wv, Wo, W1, W2, wqkv);

  ln_kernel<<<4096, 256, 0, stream>>>(x, g1, be1, hb);
  // QKV: M=4096, N=3072, K=1024 -> grid 16*24 = 384
  gemm_bt<EpiQKV><<<384, 256, 0, stream>>>(hb, wqkv, 1024, 1024, 24,
      EpiQKV{qb, kb, vtb, bq, bk, bv});
  attn_kernel<<<dim3(16, 16, 2), 256, 0, stream>>>(qb, kb, vtb, atb);
  // O-proj: N=1024, K=1024 split 2 -> grid 16*8*2 = 256
  gemm_bt<EpiPartB><<<256, 256, 0, stream>>>(atb, wob, 1024, 512, 8,
      EpiPartB{op_part});
  ln_fuse<<<4096, 256, 0, stream>>>(x, op_part, bo, g2, be2, out, hb);
  // MLP1: N=4096, K=1024 -> grid 16*32 = 512
  gemm_bt<EpiGelu><<<512, 256, 0, stream>>>(hb, w1b, 1024, 1024, 32,
      EpiGelu{b1, m1b});
  // MLP2: N=1024, K=4096 split 4 -> grid 16*8*4 = 512
  gemm_bt<EpiPartB><<<512, 256, 0, stream>>>(m1b, w2b, 4096, 1024, 8,
      EpiPartB{ml_part});
  add4<<<4096, 256, 0, stream>>>(out, ml_part, b2);
}